// Round 3
// baseline (125.550 us; speedup 1.0000x reference)
//
#include <hip/hip_runtime.h>

typedef __attribute__((ext_vector_type(8))) _Float16 f16x8;
typedef __attribute__((ext_vector_type(4))) float f32x4;
typedef __attribute__((address_space(1))) const char gc_char;
typedef __attribute__((address_space(3))) char ls_char;

#define MFMA(a, b, c) __builtin_amdgcn_mfma_f32_16x16x32_f16((a), (b), (c), 0, 0, 0)
#define FENCE() asm volatile("" ::: "memory")
#define BARRIER() do { FENCE(); __builtin_amdgcn_s_barrier(); FENCE(); } while (0)
#define VMW(n) asm volatile("s_waitcnt vmcnt(" #n ")" ::: "memory")

static constexpr int SEQ = 4096;
static constexpr int EMB = 512;
static constexpr float QSCALE = 0.04419417382415922f; // 1/sqrt(512)

__device__ __forceinline__ void gl_lds16(const void* g, void* l) {
    __builtin_amdgcn_global_load_lds((gc_char*)g, (ls_char*)l, 16, 0, 0);
}

// ---------------- fused prep: cast x + transpose-cast both W ----------------
__global__ void k_prep(const float* __restrict__ x, _Float16* __restrict__ xb,
                       const float* __restrict__ Wq, _Float16* __restrict__ WqT,
                       const float* __restrict__ Wo, _Float16* __restrict__ WoT) {
    const int bid = blockIdx.x, tid = threadIdx.x;
    if (bid < 4096) {
        long i = (long)bid * 256 + tid;
        const float4* p = (const float4*)x + i * 2;
        float4 a = p[0], b = p[1];
        f16x8 v;
        v[0] = (_Float16)a.x; v[1] = (_Float16)a.y; v[2] = (_Float16)a.z; v[3] = (_Float16)a.w;
        v[4] = (_Float16)b.x; v[5] = (_Float16)b.y; v[6] = (_Float16)b.z; v[7] = (_Float16)b.w;
        *(f16x8*)(xb + i * 8) = v;
    } else if (bid < 7168) {
        int i = (bid - 4096) * 256 + tid; // over 512*1536
        WqT[i] = (_Float16)Wq[(i & 511) * 1536 + (i >> 9)];
    } else {
        int i = (bid - 7168) * 256 + tid; // over 512*512
        WoT[i] = (_Float16)Wo[(i & 511) * 512 + (i >> 9)];
    }
}

// ================= QKV GEMM: 256x256 tile, BK=64, 8-phase counted-vmcnt =================
// Q/K written row-major fp16; V written TRANSPOSED: VT[b][e][k] (same HBM bytes).
__launch_bounds__(512, 2) __global__
void k_gemm_qkv(const _Float16* __restrict__ A, const _Float16* __restrict__ BT,
                const float* __restrict__ bias,
                _Float16* __restrict__ Qo, _Float16* __restrict__ Ko, _Float16* __restrict__ VT) {
    extern __shared__ __align__(16) char smem[];
    const int tid = threadIdx.x, w = tid >> 6, lane = tid & 63, g = lane >> 4, f = lane & 15;
    const int wrow = w >> 2, wcol = w & 3;
    const int bid = blockIdx.x;
    const int swz = (bid & 7) * 48 + (bid >> 3); // XCD swizzle, bijective (384 % 8 == 0)
    const int brow = swz / 6, bcol = swz - brow * 6;
    const long row0 = (long)brow * 256;
    const int col0 = bcol * 256;
    const char* Abase = (const char*)A + row0 * 1024;
    const char* Bbase = (const char*)BT + (long)col0 * 1024;

    f32x4 acc[8][4] = {};
    f16x8 a[4][2], b[2][2];

    auto stageA = [&](int h, char* dstbuf, int kt) {
#pragma unroll
        for (int it = 0; it < 2; ++it) {
            int s = it * 512 + tid;
            int lr = s >> 3;
            int ch = (s & 7) ^ (lr & 7);
            int r = (lr & 63) | ((lr & 64) << 1) | (h << 6);
            gl_lds16(Abase + (long)r * 1024 + kt * 128 + ch * 16, dstbuf + h * 16384 + s * 16);
        }
    };
    auto stageB = [&](int h, char* dstbuf, int kt) {
#pragma unroll
        for (int it = 0; it < 2; ++it) {
            int s = it * 512 + tid;
            int lr = s >> 3;
            int ch = (s & 7) ^ (lr & 7);
            int n = (lr & 31) | ((lr >> 5) << 6) | (h << 5);
            gl_lds16(Bbase + (long)n * 1024 + kt * 128 + ch * 16, dstbuf + h * 16384 + s * 16);
        }
    };
    auto ldA = [&](const char* buf, int mq) {
#pragma unroll
        for (int mi = 0; mi < 4; ++mi)
#pragma unroll
            for (int ks = 0; ks < 2; ++ks) {
                int r = wrow * 128 + mq * 64 + mi * 16 + f;
                int half = (r >> 6) & 1, lr = (r & 63) | ((r & 128) >> 1);
                int cl = ks * 4 + g;
                a[mi][ks] = *(const f16x8*)(buf + half * 16384 + lr * 128 + ((cl ^ (lr & 7)) << 4));
            }
    };
    auto ldB = [&](const char* buf, int nq) {
#pragma unroll
        for (int ni = 0; ni < 2; ++ni)
#pragma unroll
            for (int ks = 0; ks < 2; ++ks) {
                int n = wcol * 64 + nq * 32 + ni * 16 + f;
                int half = (n >> 5) & 1, lr = (n & 31) | (((n >> 6) & 3) << 5);
                int cl = ks * 4 + g;
                b[ni][ks] = *(const f16x8*)(buf + half * 16384 + lr * 128 + ((cl ^ (lr & 7)) << 4));
            }
    };
    auto mfma16 = [&](int mq, int nq) {
        __builtin_amdgcn_s_setprio(1);
#pragma unroll
        for (int mi = 0; mi < 4; ++mi)
#pragma unroll
            for (int ni = 0; ni < 2; ++ni)
#pragma unroll
                for (int ks = 0; ks < 2; ++ks)
                    acc[mq * 4 + mi][nq * 2 + ni] = MFMA(a[mi][ks], b[ni][ks], acc[mq * 4 + mi][nq * 2 + ni]);
        __builtin_amdgcn_s_setprio(0);
    };

    {
        char* A0 = smem;
        char* B0 = smem + 32768;
        stageA(0, A0, 0); stageB(0, B0, 0); stageB(1, B0, 0); stageA(1, A0, 0);
    }
    VMW(4);
    BARRIER();

    for (int kt = 0; kt < 8; ++kt) {
        const char* Ac = smem + (kt & 1) * 65536;
        const char* Bc = Ac + 32768;
        char* An = smem + ((kt + 1) & 1) * 65536;
        char* Bn = An + 32768;
        const bool last = (kt == 7);
        ldA(Ac, 0); ldB(Bc, 0);
        if (!last) stageA(0, An, kt + 1);
        BARRIER();
        mfma16(0, 0);
        if (!last) { VMW(4); } else { VMW(2); }
        BARRIER();
        ldB(Bc, 1);
        if (!last) stageB(0, Bn, kt + 1);
        BARRIER();
        mfma16(0, 1);
        if (!last) { VMW(4); } else { VMW(0); }
        BARRIER();
        ldA(Ac, 1); ldB(Bc, 0);
        if (!last) stageB(1, Bn, kt + 1);
        BARRIER();
        mfma16(1, 0);
        BARRIER();
        ldB(Bc, 1);
        if (!last) stageA(1, An, kt + 1);
        BARRIER();
        mfma16(1, 1);
        if (!last) { VMW(4); }
        BARRIER();
    }

    // ---- epilogue: acc -> LDS (bias+scale, fp16, rotation swizzle) ----
    float bv[4];
    const float sc = (col0 < 512) ? QSCALE : 1.0f;
#pragma unroll
    for (int ni = 0; ni < 4; ++ni) bv[ni] = bias[col0 + wcol * 64 + ni * 16 + f];
#pragma unroll
    for (int mi = 0; mi < 8; ++mi)
#pragma unroll
        for (int ni = 0; ni < 4; ++ni)
#pragma unroll
            for (int j = 0; j < 4; ++j) {
                int r = wrow * 128 + mi * 16 + g * 4 + j;
                int c = wcol * 64 + ni * 16 + f;
                float v = (acc[mi][ni][j] + bv[ni]) * sc;
                int pc = ((c >> 3) + ((r >> 2) & 7) * 2) & 31;
                *(_Float16*)(smem + r * 512 + pc * 16 + (c & 7) * 2) = (_Float16)v;
            }
    __syncthreads();

    if (col0 >= 1024) {
        // V: transposed store VT[b][e][k]
        int bb = (int)(row0 >> 12);
        _Float16* vt = VT + ((long)bb * 512 + (col0 - 1024)) * 4096 + (row0 & 4095);
#pragma unroll
        for (int it = 0; it < 16; ++it) {
            int kc = tid & 31;            // 8-row k-chunk
            int e = it * 16 + (tid >> 5); // local e col
            f16x8 v;
#pragma unroll
            for (int j = 0; j < 8; ++j) {
                int r = kc * 8 + j;
                int pc = ((e >> 3) + ((r >> 2) & 7) * 2) & 31;
                v[j] = *(const _Float16*)(smem + r * 512 + pc * 16 + (e & 7) * 2);
            }
            *(f16x8*)(vt + (long)e * 4096 + kc * 8) = v;
        }
    } else {
        _Float16* dst = (col0 < 512) ? Qo : Ko;
        int cofs = (col0 < 512) ? col0 : col0 - 512;
#pragma unroll
        for (int it = 0; it < 16; ++it) {
            int r = it * 16 + (tid >> 5);
            int ch = tid & 31;
            int pc = (ch + ((r >> 2) & 7) * 2) & 31;
            f16x8 v = *(const f16x8*)(smem + r * 512 + pc * 16);
            *(f16x8*)(dst + (row0 + r) * 512 + cofs + ch * 8) = v;
        }
    }
}

// ================= out-projection GEMM (m97-style 128x128) =================
__launch_bounds__(256, 2) __global__
void k_gemm_out(const _Float16* __restrict__ A, const _Float16* __restrict__ BT,
                const float* __restrict__ bias, float* __restrict__ out) {
    __shared__ __align__(16) _Float16 As[128 * 64];
    __shared__ __align__(16) _Float16 Bs[128 * 64];
    const int tid = threadIdx.x, w = tid >> 6, lane = tid & 63, g = lane >> 4, f = lane & 15;
    const int wr = w >> 1, wc = w & 1;
    const long row0 = (long)blockIdx.x * 128, col0 = (long)blockIdx.y * 128;
    f32x4 acc[4][4] = {};
    const char* Ab = (const char*)(A + row0 * 512);
    const char* Bb = (const char*)(BT + col0 * 512);

    for (int kt = 0; kt < 8; ++kt) {
        __syncthreads();
        const char* Asrc = Ab + kt * 128;
        const char* Bsrc = Bb + kt * 128;
#pragma unroll
        for (int it = 0; it < 4; ++it) {
            int slot = it * 256 + tid;
            int r = slot >> 3, ch = slot & 7;
            int scol = (ch * 16) ^ ((r & 7) << 4);
            gl_lds16(Asrc + (long)r * 1024 + scol, (char*)As + (it * 256 + (tid & 0xC0)) * 16);
            gl_lds16(Bsrc + (long)r * 1024 + scol, (char*)Bs + (it * 256 + (tid & 0xC0)) * 16);
        }
        __syncthreads();
#pragma unroll
        for (int ks = 0; ks < 2; ++ks) {
            f16x8 af[4], bf[4];
#pragma unroll
            for (int mi = 0; mi < 4; ++mi) {
                int r = wr * 64 + mi * 16 + f;
                af[mi] = *(const f16x8*)((const char*)As + r * 128 + ((ks * 64 + g * 16) ^ ((r & 7) << 4)));
            }
#pragma unroll
            for (int ni = 0; ni < 4; ++ni) {
                int r = wc * 64 + ni * 16 + f;
                bf[ni] = *(const f16x8*)((const char*)Bs + r * 128 + ((ks * 64 + g * 16) ^ ((r & 7) << 4)));
            }
#pragma unroll
            for (int mi = 0; mi < 4; ++mi)
#pragma unroll
                for (int ni = 0; ni < 4; ++ni)
                    acc[mi][ni] = MFMA(af[mi], bf[ni], acc[mi][ni]);
        }
    }
#pragma unroll
    for (int mi = 0; mi < 4; ++mi)
#pragma unroll
        for (int ni = 0; ni < 4; ++ni) {
            long r0 = row0 + wr * 64 + mi * 16 + g * 4;
            int c = (int)col0 + wc * 64 + ni * 16 + f;
            float bv = bias[c];
#pragma unroll
            for (int j = 0; j < 4; ++j)
                out[(r0 + j) * 512 + c] = acc[mi][ni][j] + bv;
        }
}

// ================= windowed attention: QBLK=32, grid 512, V^T from global =================
// 4 waves: rh = w&1 (16-row half), kh = w>>1 (80-key half for QK^T, 256-e half for PV).
__launch_bounds__(256, 2) __global__
void k_attn(const _Float16* __restrict__ Qb, const _Float16* __restrict__ Kb,
            const _Float16* __restrict__ VT, _Float16* __restrict__ Ob) {
    __shared__ __align__(16) _Float16 Pl[32 * 168]; // [q row][key], stride 336B
    __shared__ float Mp[2][32];
    __shared__ float Lp[2][32];
    const int tid = threadIdx.x, w = tid >> 6, lane = tid & 63, g = lane >> 4, f = lane & 15;
    const int rh = w & 1, kh = w >> 1;
    const int b = blockIdx.x >> 7, qt = blockIdx.x & 127;
    const int q0 = qt * 32, kbase = q0 - 64; // 160-key span
    const long bofs = (long)b * SEQ;
    const int row = rh * 16 + g * 4; // this lane's first q-row (local)

    // ---- QK^T: 16 q-rows x 80 keys (5 tiles) ----
    const _Float16* qrow = Qb + (bofs + q0 + rh * 16 + f) * EMB + g * 8;
    const _Float16* kp[5];
#pragma unroll
    for (int t = 0; t < 5; ++t) {
        int key = kbase + kh * 80 + t * 16 + f;
        key = min(max(key, 0), SEQ - 1);
        kp[t] = Kb + (bofs + key) * EMB + g * 8;
    }
    f32x4 sacc[5] = {};
#pragma unroll
    for (int ks = 0; ks < 16; ++ks) {
        f16x8 qf = *(const f16x8*)(qrow + ks * 32);
#pragma unroll
        for (int t = 0; t < 5; ++t)
            sacc[t] = MFMA(qf, *(const f16x8*)(kp[t] + ks * 32), sacc[t]);
    }

    // ---- mask + two-wave softmax ----
    const int qr0 = q0 + rh * 16 + g * 4;
    float m[4] = {-3e30f, -3e30f, -3e30f, -3e30f}, l[4] = {0.f, 0.f, 0.f, 0.f};
#pragma unroll
    for (int t = 0; t < 5; ++t) {
        int key = kbase + kh * 80 + t * 16 + f;
        bool kv = (key >= 0) && (key < SEQ);
#pragma unroll
        for (int j = 0; j < 4; ++j) {
            int d = key - (qr0 + j);
            bool valid = kv && (d >= -64) && (d <= 64);
            float s = valid ? sacc[t][j] : -3e30f;
            sacc[t][j] = s;
            m[j] = fmaxf(m[j], s);
        }
    }
#pragma unroll
    for (int j = 0; j < 4; ++j) {
        m[j] = fmaxf(m[j], __shfl_xor(m[j], 1));
        m[j] = fmaxf(m[j], __shfl_xor(m[j], 2));
        m[j] = fmaxf(m[j], __shfl_xor(m[j], 4));
        m[j] = fmaxf(m[j], __shfl_xor(m[j], 8));
    }
    if (f == 0) {
#pragma unroll
        for (int j = 0; j < 4; ++j) Mp[kh][row + j] = m[j];
    }
    __syncthreads();
#pragma unroll
    for (int j = 0; j < 4; ++j) m[j] = fmaxf(m[j], Mp[kh ^ 1][row + j]);

#pragma unroll
    for (int t = 0; t < 5; ++t)
#pragma unroll
        for (int j = 0; j < 4; ++j) {
            float p = __expf(sacc[t][j] - m[j]);
            sacc[t][j] = p;
            l[j] += p;
        }
#pragma unroll
    for (int j = 0; j < 4; ++j) {
        l[j] += __shfl_xor(l[j], 1);
        l[j] += __shfl_xor(l[j], 2);
        l[j] += __shfl_xor(l[j], 4);
        l[j] += __shfl_xor(l[j], 8);
    }
    if (f == 0) {
#pragma unroll
        for (int j = 0; j < 4; ++j) Lp[kh][row + j] = l[j];
    }
    // P -> LDS
#pragma unroll
    for (int t = 0; t < 5; ++t)
#pragma unroll
        for (int j = 0; j < 4; ++j)
            Pl[(row + j) * 168 + kh * 80 + t * 16 + f] = (_Float16)sacc[t][j];
    __syncthreads();
    float rl[4];
#pragma unroll
    for (int j = 0; j < 4; ++j) rl[j] = 1.0f / (l[j] + Lp[kh ^ 1][row + j]);

    // ---- PV: 16 q-rows x 256-e half; B-frags straight from VT[b][e][k] ----
    f16x8 pf[5];
#pragma unroll
    for (int kc = 0; kc < 5; ++kc)
        pf[kc] = *(const f16x8*)((const char*)Pl + (rh * 16 + f) * 336 + kc * 64 + g * 16);
    int kcl[5];
#pragma unroll
    for (int kc = 0; kc < 5; ++kc)
        kcl[kc] = min(max(kbase + kc * 32 + g * 8, 0), SEQ - 8);
    const _Float16* vtb = VT + ((long)b * 512 + kh * 256 + f) * 4096;
    _Float16* ob = Ob + (bofs + q0 + rh * 16 + g * 4) * EMB + kh * 256 + f;
#pragma unroll
    for (int ni = 0; ni < 16; ++ni) {
        f32x4 o = {};
#pragma unroll
        for (int kc = 0; kc < 5; ++kc) {
            f16x8 vf = *(const f16x8*)(vtb + (long)ni * 16 * 4096 + kcl[kc]);
            o = MFMA(pf[kc], vf, o);
        }
#pragma unroll
        for (int j = 0; j < 4; ++j)
            ob[(long)j * EMB + ni * 16] = (_Float16)(o[j] * rl[j]);
    }
}

extern "C" void kernel_launch(void* const* d_in, const int* in_sizes, int n_in,
                              void* d_out, int out_size, void* d_ws, size_t ws_size,
                              hipStream_t stream) {
    const float* x     = (const float*)d_in[0];
    const float* W_qkv = (const float*)d_in[1];
    const float* b_qkv = (const float*)d_in[2];
    const float* W_out = (const float*)d_in[3];
    const float* b_out = (const float*)d_in[4];

    char* ws = (char*)d_ws;
    _Float16* xb    = (_Float16*)(ws);                         // 16 MiB
    _Float16* WqkvT = (_Float16*)(ws + 16777216);              // 1.5 MiB
    _Float16* WoutT = (_Float16*)(ws + 16777216 + 1572864);    // 0.5 MiB
    _Float16* Qb    = (_Float16*)(ws + 18874368);              // 16 MiB
    _Float16* Kb    = (_Float16*)(ws + 18874368 + 16777216);   // 16 MiB
    _Float16* VT    = (_Float16*)(ws + 18874368 + 33554432);   // 16 MiB [b][e][k]
    _Float16* Ob    = xb; // reuse xb (dead after QKV GEMM)
    float* out = (float*)d_out;

    (void)hipFuncSetAttribute((const void*)k_gemm_qkv,
                              hipFuncAttributeMaxDynamicSharedMemorySize, 131072);

    k_prep<<<8192, 256, 0, stream>>>(x, xb, W_qkv, WqkvT, W_out, WoutT);
    k_gemm_qkv<<<384, 512, 131072, stream>>>(xb, WqkvT, b_qkv, Qb, Kb, VT);
    k_attn<<<512, 256, 0, stream>>>(Qb, Kb, VT, Ob);
    dim3 g2(128, 4);
    k_gemm_out<<<g2, 256, 0, stream>>>(Ob, WoutT, b_out, out);
}

// Round 4
// 121.890 us; speedup vs baseline: 1.0300x; 1.0300x over previous
//
#include <hip/hip_runtime.h>

typedef __attribute__((ext_vector_type(8))) _Float16 f16x8;
typedef __attribute__((ext_vector_type(4))) _Float16 f16x4;
typedef __attribute__((ext_vector_type(4))) float f32x4;
typedef __attribute__((address_space(1))) const char gc_char;
typedef __attribute__((address_space(3))) char ls_char;

#define MFMA(a, b, c) __builtin_amdgcn_mfma_f32_16x16x32_f16((a), (b), (c), 0, 0, 0)
#define FENCE() asm volatile("" ::: "memory")
#define BARRIER() do { FENCE(); __builtin_amdgcn_s_barrier(); FENCE(); } while (0)
#define VMW(n) asm volatile("s_waitcnt vmcnt(" #n ")" ::: "memory")

static constexpr int SEQ = 4096;
static constexpr int EMB = 512;
static constexpr float QSCALE = 0.04419417382415922f; // 1/sqrt(512)

__device__ __forceinline__ void gl_lds16(const void* g, void* l) {
    __builtin_amdgcn_global_load_lds((gc_char*)g, (ls_char*)l, 16, 0, 0);
}

// ---------------- fused prep: cast x + transpose-cast both W ----------------
__global__ void k_prep(const float* __restrict__ x, _Float16* __restrict__ xb,
                       const float* __restrict__ Wq, _Float16* __restrict__ WqT,
                       const float* __restrict__ Wo, _Float16* __restrict__ WoT) {
    const int bid = blockIdx.x, tid = threadIdx.x;
    if (bid < 4096) {
        long i = (long)bid * 256 + tid;
        const float4* p = (const float4*)x + i * 2;
        float4 a = p[0], b = p[1];
        f16x8 v;
        v[0] = (_Float16)a.x; v[1] = (_Float16)a.y; v[2] = (_Float16)a.z; v[3] = (_Float16)a.w;
        v[4] = (_Float16)b.x; v[5] = (_Float16)b.y; v[6] = (_Float16)b.z; v[7] = (_Float16)b.w;
        *(f16x8*)(xb + i * 8) = v;
    } else if (bid < 7168) {
        int i = (bid - 4096) * 256 + tid; // over 512*1536
        WqT[i] = (_Float16)Wq[(i & 511) * 1536 + (i >> 9)];
    } else {
        int i = (bid - 7168) * 256 + tid; // over 512*512
        WoT[i] = (_Float16)Wo[(i & 511) * 512 + (i >> 9)];
    }
}

// ================= QKV GEMM: 256x256 tile, BK=64, 8-phase counted-vmcnt =================
// Q/K row-major fp16; V written TRANSPOSED via packed-b64 LDS transpose: VT[b][e][k].
__launch_bounds__(512, 2) __global__
void k_gemm_qkv(const _Float16* __restrict__ A, const _Float16* __restrict__ BT,
                const float* __restrict__ bias,
                _Float16* __restrict__ Qo, _Float16* __restrict__ Ko, _Float16* __restrict__ VT) {
    extern __shared__ __align__(16) char smem[];
    const int tid = threadIdx.x, w = tid >> 6, lane = tid & 63, g = lane >> 4, f = lane & 15;
    const int wrow = w >> 2, wcol = w & 3;
    const int bid = blockIdx.x;
    const int swz = (bid & 7) * 48 + (bid >> 3); // XCD swizzle, bijective (384 % 8 == 0)
    const int brow = swz / 6, bcol = swz - brow * 6;
    const long row0 = (long)brow * 256;
    const int col0 = bcol * 256;
    const char* Abase = (const char*)A + row0 * 1024;
    const char* Bbase = (const char*)BT + (long)col0 * 1024;

    f32x4 acc[8][4] = {};
    f16x8 a[4][2], b[2][2];

    auto stageA = [&](int h, char* dstbuf, int kt) {
#pragma unroll
        for (int it = 0; it < 2; ++it) {
            int s = it * 512 + tid;
            int lr = s >> 3;
            int ch = (s & 7) ^ (lr & 7);
            int r = (lr & 63) | ((lr & 64) << 1) | (h << 6);
            gl_lds16(Abase + (long)r * 1024 + kt * 128 + ch * 16, dstbuf + h * 16384 + s * 16);
        }
    };
    auto stageB = [&](int h, char* dstbuf, int kt) {
#pragma unroll
        for (int it = 0; it < 2; ++it) {
            int s = it * 512 + tid;
            int lr = s >> 3;
            int ch = (s & 7) ^ (lr & 7);
            int n = (lr & 31) | ((lr >> 5) << 6) | (h << 5);
            gl_lds16(Bbase + (long)n * 1024 + kt * 128 + ch * 16, dstbuf + h * 16384 + s * 16);
        }
    };
    auto ldA = [&](const char* buf, int mq) {
#pragma unroll
        for (int mi = 0; mi < 4; ++mi)
#pragma unroll
            for (int ks = 0; ks < 2; ++ks) {
                int r = wrow * 128 + mq * 64 + mi * 16 + f;
                int half = (r >> 6) & 1, lr = (r & 63) | ((r & 128) >> 1);
                int cl = ks * 4 + g;
                a[mi][ks] = *(const f16x8*)(buf + half * 16384 + lr * 128 + ((cl ^ (lr & 7)) << 4));
            }
    };
    auto ldB = [&](const char* buf, int nq) {
#pragma unroll
        for (int ni = 0; ni < 2; ++ni)
#pragma unroll
            for (int ks = 0; ks < 2; ++ks) {
                int n = wcol * 64 + nq * 32 + ni * 16 + f;
                int half = (n >> 5) & 1, lr = (n & 31) | (((n >> 6) & 3) << 5);
                int cl = ks * 4 + g;
                b[ni][ks] = *(const f16x8*)(buf + half * 16384 + lr * 128 + ((cl ^ (lr & 7)) << 4));
            }
    };
    auto mfma16 = [&](int mq, int nq) {
        __builtin_amdgcn_s_setprio(1);
#pragma unroll
        for (int mi = 0; mi < 4; ++mi)
#pragma unroll
            for (int ni = 0; ni < 2; ++ni)
#pragma unroll
                for (int ks = 0; ks < 2; ++ks)
                    acc[mq * 4 + mi][nq * 2 + ni] = MFMA(a[mi][ks], b[ni][ks], acc[mq * 4 + mi][nq * 2 + ni]);
        __builtin_amdgcn_s_setprio(0);
    };

    {
        char* A0 = smem;
        char* B0 = smem + 32768;
        stageA(0, A0, 0); stageB(0, B0, 0); stageB(1, B0, 0); stageA(1, A0, 0);
    }
    VMW(4);
    BARRIER();

    for (int kt = 0; kt < 8; ++kt) {
        const char* Ac = smem + (kt & 1) * 65536;
        const char* Bc = Ac + 32768;
        char* An = smem + ((kt + 1) & 1) * 65536;
        char* Bn = An + 32768;
        const bool last = (kt == 7);
        ldA(Ac, 0); ldB(Bc, 0);
        if (!last) stageA(0, An, kt + 1);
        BARRIER();
        mfma16(0, 0);
        if (!last) { VMW(4); } else { VMW(2); }
        BARRIER();
        ldB(Bc, 1);
        if (!last) stageB(0, Bn, kt + 1);
        BARRIER();
        mfma16(0, 1);
        if (!last) { VMW(4); } else { VMW(0); }
        BARRIER();
        ldA(Ac, 1); ldB(Bc, 0);
        if (!last) stageB(1, Bn, kt + 1);
        BARRIER();
        mfma16(1, 0);
        BARRIER();
        ldB(Bc, 1);
        if (!last) stageA(1, An, kt + 1);
        BARRIER();
        mfma16(1, 1);
        if (!last) { VMW(4); }
        BARRIER();
    }

    float bv[4];
#pragma unroll
    for (int ni = 0; ni < 4; ++ni) bv[ni] = bias[col0 + wcol * 64 + ni * 16 + f];

    if (col0 >= 1024) {
        // ---- V: packed transposed LDS write T[e][k], byte = e*512 + (k*2 ^ ((e&7)<<4)) ----
#pragma unroll
        for (int mi = 0; mi < 8; ++mi)
#pragma unroll
            for (int ni = 0; ni < 4; ++ni) {
                int r0 = wrow * 128 + mi * 16 + g * 4; // k index (4 consecutive j)
                int c = wcol * 64 + ni * 16 + f;       // e index
                f16x4 v4;
#pragma unroll
                for (int j = 0; j < 4; ++j) v4[j] = (_Float16)(acc[mi][ni][j] + bv[ni]);
                *(f16x4*)(smem + c * 512 + ((r0 * 2) ^ ((c & 7) << 4))) = v4;
            }
        __syncthreads();
        int bb = (int)(row0 >> 12);
        _Float16* vt = VT + ((long)bb * 512 + (col0 - 1024)) * 4096 + (row0 & 4095);
#pragma unroll
        for (int it = 0; it < 16; ++it) {
            int e = it * 16 + (tid >> 5);
            int ch = tid & 31;
            f16x8 v = *(const f16x8*)(smem + e * 512 + ((ch * 16) ^ ((e & 7) << 4)));
            *(f16x8*)(vt + (long)e * 4096 + ch * 8) = v;
        }
    } else {
        // ---- Q/K: rotation-swizzle row-major epilogue ----
        const float sc = (col0 < 512) ? QSCALE : 1.0f;
#pragma unroll
        for (int mi = 0; mi < 8; ++mi)
#pragma unroll
            for (int ni = 0; ni < 4; ++ni)
#pragma unroll
                for (int j = 0; j < 4; ++j) {
                    int r = wrow * 128 + mi * 16 + g * 4 + j;
                    int c = wcol * 64 + ni * 16 + f;
                    float v = (acc[mi][ni][j] + bv[ni]) * sc;
                    int pc = ((c >> 3) + ((r >> 2) & 7) * 2) & 31;
                    *(_Float16*)(smem + r * 512 + pc * 16 + (c & 7) * 2) = (_Float16)v;
                }
        __syncthreads();
        _Float16* dst = (col0 < 512) ? Qo : Ko;
        int cofs = (col0 < 512) ? col0 : col0 - 512;
#pragma unroll
        for (int it = 0; it < 16; ++it) {
            int r = it * 16 + (tid >> 5);
            int ch = tid & 31;
            int pc = (ch + ((r >> 2) & 7) * 2) & 31;
            f16x8 v = *(const f16x8*)(smem + r * 512 + pc * 16);
            *(f16x8*)(dst + (row0 + r) * 512 + cofs + ch * 8) = v;
        }
    }
}

// ================= out-projection GEMM (m97-style 128x128) =================
__launch_bounds__(256, 2) __global__
void k_gemm_out(const _Float16* __restrict__ A, const _Float16* __restrict__ BT,
                const float* __restrict__ bias, float* __restrict__ out) {
    __shared__ __align__(16) _Float16 As[128 * 64];
    __shared__ __align__(16) _Float16 Bs[128 * 64];
    const int tid = threadIdx.x, w = tid >> 6, lane = tid & 63, g = lane >> 4, f = lane & 15;
    const int wr = w >> 1, wc = w & 1;
    const long row0 = (long)blockIdx.x * 128, col0 = (long)blockIdx.y * 128;
    f32x4 acc[4][4] = {};
    const char* Ab = (const char*)(A + row0 * 512);
    const char* Bb = (const char*)(BT + col0 * 512);

    for (int kt = 0; kt < 8; ++kt) {
        __syncthreads();
        const char* Asrc = Ab + kt * 128;
        const char* Bsrc = Bb + kt * 128;
#pragma unroll
        for (int it = 0; it < 4; ++it) {
            int slot = it * 256 + tid;
            int r = slot >> 3, ch = slot & 7;
            int scol = (ch * 16) ^ ((r & 7) << 4);
            gl_lds16(Asrc + (long)r * 1024 + scol, (char*)As + (it * 256 + (tid & 0xC0)) * 16);
            gl_lds16(Bsrc + (long)r * 1024 + scol, (char*)Bs + (it * 256 + (tid & 0xC0)) * 16);
        }
        __syncthreads();
#pragma unroll
        for (int ks = 0; ks < 2; ++ks) {
            f16x8 af[4], bf[4];
#pragma unroll
            for (int mi = 0; mi < 4; ++mi) {
                int r = wr * 64 + mi * 16 + f;
                af[mi] = *(const f16x8*)((const char*)As + r * 128 + ((ks * 64 + g * 16) ^ ((r & 7) << 4)));
            }
#pragma unroll
            for (int ni = 0; ni < 4; ++ni) {
                int r = wc * 64 + ni * 16 + f;
                bf[ni] = *(const f16x8*)((const char*)Bs + r * 128 + ((ks * 64 + g * 16) ^ ((r & 7) << 4)));
            }
#pragma unroll
            for (int mi = 0; mi < 4; ++mi)
#pragma unroll
                for (int ni = 0; ni < 4; ++ni)
                    acc[mi][ni] = MFMA(af[mi], bf[ni], acc[mi][ni]);
        }
    }
#pragma unroll
    for (int mi = 0; mi < 4; ++mi)
#pragma unroll
        for (int ni = 0; ni < 4; ++ni) {
            long r0 = row0 + wr * 64 + mi * 16 + g * 4;
            int c = (int)col0 + wc * 64 + ni * 16 + f;
            float bv = bias[c];
#pragma unroll
            for (int j = 0; j < 4; ++j)
                out[(r0 + j) * 512 + c] = acc[mi][ni][j] + bv;
        }
}

// ================= windowed attention: QBLK=16, grid 1024, 4 blocks/CU =================
// 4 waves: wave w handles keys [w*48, w*48+48) of the 192-key span (QK^T) and
// e-range [w*128, w*128+128) (PV). 4-way softmax combine via Mp/Lp.
__launch_bounds__(256, 4) __global__
void k_attn(const _Float16* __restrict__ Qb, const _Float16* __restrict__ Kb,
            const _Float16* __restrict__ VT, _Float16* __restrict__ Ob) {
    __shared__ __align__(16) _Float16 Pl[16 * 200]; // [q row][key], stride 400B
    __shared__ float Mp[4][16];
    __shared__ float Lp[4][16];
    const int tid = threadIdx.x, w = tid >> 6, lane = tid & 63, g = lane >> 4, f = lane & 15;
    const int bid = blockIdx.x;
    const int swzb = (bid & 7) * 128 + (bid >> 3); // XCD swizzle (1024 % 8 == 0)
    const int b = swzb >> 8, qt = swzb & 255;
    const int q0 = qt * 16, kbase = q0 - 64; // 192-key padded span
    const long bofs = (long)b * SEQ;
    const int row = g * 4; // lane's first local q-row

    // ---- QK^T: 16 rows x 48 keys (3 tiles) per wave ----
    const _Float16* qrow = Qb + (bofs + q0 + f) * EMB + g * 8;
    const _Float16* kp[3];
#pragma unroll
    for (int t = 0; t < 3; ++t) {
        int key = kbase + w * 48 + t * 16 + f;
        key = min(max(key, 0), SEQ - 1);
        kp[t] = Kb + (bofs + key) * EMB + g * 8;
    }
    f32x4 sacc[3] = {};
#pragma unroll
    for (int ks = 0; ks < 16; ++ks) {
        f16x8 qf = *(const f16x8*)(qrow + ks * 32);
#pragma unroll
        for (int t = 0; t < 3; ++t)
            sacc[t] = MFMA(qf, *(const f16x8*)(kp[t] + ks * 32), sacc[t]);
    }

    // ---- mask + 4-way wave softmax ----
    float m[4] = {-3e30f, -3e30f, -3e30f, -3e30f}, l[4] = {0.f, 0.f, 0.f, 0.f};
#pragma unroll
    for (int t = 0; t < 3; ++t) {
        int key = kbase + w * 48 + t * 16 + f;
        bool kv = (key >= 0) && (key < SEQ);
#pragma unroll
        for (int j = 0; j < 4; ++j) {
            int d = key - (q0 + row + j);
            bool valid = kv && (d >= -64) && (d <= 64);
            float s = valid ? sacc[t][j] : -3e30f;
            sacc[t][j] = s;
            m[j] = fmaxf(m[j], s);
        }
    }
#pragma unroll
    for (int j = 0; j < 4; ++j) {
        m[j] = fmaxf(m[j], __shfl_xor(m[j], 1));
        m[j] = fmaxf(m[j], __shfl_xor(m[j], 2));
        m[j] = fmaxf(m[j], __shfl_xor(m[j], 4));
        m[j] = fmaxf(m[j], __shfl_xor(m[j], 8));
    }
    if (f == 0) {
#pragma unroll
        for (int j = 0; j < 4; ++j) Mp[w][row + j] = m[j];
    }
    __syncthreads();
#pragma unroll
    for (int j = 0; j < 4; ++j) {
        m[j] = fmaxf(fmaxf(Mp[0][row + j], Mp[1][row + j]),
                     fmaxf(Mp[2][row + j], Mp[3][row + j]));
    }
#pragma unroll
    for (int t = 0; t < 3; ++t)
#pragma unroll
        for (int j = 0; j < 4; ++j) {
            float p = __expf(sacc[t][j] - m[j]);
            sacc[t][j] = p;
            l[j] += p;
        }
#pragma unroll
    for (int j = 0; j < 4; ++j) {
        l[j] += __shfl_xor(l[j], 1);
        l[j] += __shfl_xor(l[j], 2);
        l[j] += __shfl_xor(l[j], 4);
        l[j] += __shfl_xor(l[j], 8);
    }
    if (f == 0) {
#pragma unroll
        for (int j = 0; j < 4; ++j) Lp[w][row + j] = l[j];
    }
#pragma unroll
    for (int t = 0; t < 3; ++t)
#pragma unroll
        for (int j = 0; j < 4; ++j)
            Pl[(row + j) * 200 + w * 48 + t * 16 + f] = (_Float16)sacc[t][j];
    __syncthreads();
    float rl[4];
#pragma unroll
    for (int j = 0; j < 4; ++j)
        rl[j] = 1.0f / (Lp[0][row + j] + Lp[1][row + j] + Lp[2][row + j] + Lp[3][row + j]);

    // ---- PV: 16 rows x 128-e quarter per wave; B-frags from VT[b][e][k] ----
    f16x8 pf[6];
#pragma unroll
    for (int kc = 0; kc < 6; ++kc)
        pf[kc] = *(const f16x8*)((const char*)Pl + f * 400 + kc * 64 + g * 16);
    int kcl[6];
#pragma unroll
    for (int kc = 0; kc < 6; ++kc)
        kcl[kc] = min(max(kbase + kc * 32 + g * 8, 0), SEQ - 8);
    const _Float16* vtb = VT + ((long)b * 512 + w * 128 + f) * 4096;
    _Float16* ob = Ob + (bofs + q0 + row) * EMB + w * 128 + f;
#pragma unroll
    for (int ni = 0; ni < 8; ++ni) {
        f32x4 o = {};
#pragma unroll
        for (int kc = 0; kc < 6; ++kc) {
            f16x8 vf = *(const f16x8*)(vtb + (long)ni * 16 * 4096 + kcl[kc]);
            o = MFMA(pf[kc], vf, o);
        }
#pragma unroll
        for (int j = 0; j < 4; ++j)
            ob[(long)j * EMB + ni * 16] = (_Float16)(o[j] * rl[j]);
    }
}

extern "C" void kernel_launch(void* const* d_in, const int* in_sizes, int n_in,
                              void* d_out, int out_size, void* d_ws, size_t ws_size,
                              hipStream_t stream) {
    const float* x     = (const float*)d_in[0];
    const float* W_qkv = (const float*)d_in[1];
    const float* b_qkv = (const float*)d_in[2];
    const float* W_out = (const float*)d_in[3];
    const float* b_out = (const float*)d_in[4];

    char* ws = (char*)d_ws;
    _Float16* xb    = (_Float16*)(ws);                         // 16 MiB
    _Float16* WqkvT = (_Float16*)(ws + 16777216);              // 1.5 MiB
    _Float16* WoutT = (_Float16*)(ws + 16777216 + 1572864);    // 0.5 MiB
    _Float16* Qb    = (_Float16*)(ws + 18874368);              // 16 MiB
    _Float16* Kb    = (_Float16*)(ws + 18874368 + 16777216);   // 16 MiB
    _Float16* VT    = (_Float16*)(ws + 18874368 + 33554432);   // 16 MiB [b][e][k]
    _Float16* Ob    = xb; // reuse xb (dead after QKV GEMM)
    float* out = (float*)d_out;

    (void)hipFuncSetAttribute((const void*)k_gemm_qkv,
                              hipFuncAttributeMaxDynamicSharedMemorySize, 131072);

    k_prep<<<8192, 256, 0, stream>>>(x, xb, W_qkv, WqkvT, W_out, WoutT);
    k_gemm_qkv<<<384, 512, 131072, stream>>>(xb, WqkvT, b_qkv, Qb, Kb, VT);
    k_attn<<<1024, 256, 0, stream>>>(Qb, Kb, VT, Ob);
    dim3 g2(128, 4);
    k_gemm_out<<<g2, 256, 0, stream>>>(Ob, WoutT, b_out, out);
}

// Round 5
// 87.614 us; speedup vs baseline: 1.4330x; 1.3912x over previous
//
#include <hip/hip_runtime.h>

typedef __attribute__((ext_vector_type(8))) _Float16 f16x8;
typedef __attribute__((ext_vector_type(4))) _Float16 f16x4;
typedef __attribute__((ext_vector_type(4))) float f32x4;
typedef __attribute__((address_space(1))) const char gc_char;
typedef __attribute__((address_space(3))) char ls_char;

#define MFMA(a, b, c) __builtin_amdgcn_mfma_f32_16x16x32_f16((a), (b), (c), 0, 0, 0)
#define FENCE() asm volatile("" ::: "memory")
#define BARRIER() do { FENCE(); __builtin_amdgcn_s_barrier(); FENCE(); } while (0)
#define VMW(n) asm volatile("s_waitcnt vmcnt(" #n ")" ::: "memory")

static constexpr int SEQ = 4096;
static constexpr int EMB = 512;
static constexpr float QSCALE = 0.04419417382415922f; // 1/sqrt(512)

__device__ __forceinline__ void gl_lds16(const void* g, void* l) {
    __builtin_amdgcn_global_load_lds((gc_char*)g, (ls_char*)l, 16, 0, 0);
}

// ---------------- fused prep: cast x + LDS-tiled transpose-cast both W ----------------
__global__ void k_prep(const float* __restrict__ x, _Float16* __restrict__ xb,
                       const float* __restrict__ Wq, _Float16* __restrict__ WqT,
                       const float* __restrict__ Wo, _Float16* __restrict__ WoT) {
    const int bid = blockIdx.x, tid = threadIdx.x;
    if (bid < 4096) {
        long i = (long)bid * 256 + tid;
        const float4* p = (const float4*)x + i * 2;
        float4 a = p[0], b = p[1];
        f16x8 v;
        v[0] = (_Float16)a.x; v[1] = (_Float16)a.y; v[2] = (_Float16)a.z; v[3] = (_Float16)a.w;
        v[4] = (_Float16)b.x; v[5] = (_Float16)b.y; v[6] = (_Float16)b.z; v[7] = (_Float16)b.w;
        *(f16x8*)(xb + i * 8) = v;
    } else {
        __shared__ float Ls[64][65];
        int t = bid - 4096;
        const float* W; _Float16* WT; int N, k0, n0;
        if (t < 192) { W = Wq; WT = WqT; N = 1536; k0 = (t & 7) * 64; n0 = (t >> 3) * 64; }
        else { t -= 192; W = Wo; WT = WoT; N = 512; k0 = (t & 7) * 64; n0 = (t >> 3) * 64; }
        int c = tid & 63, r4 = tid >> 6;
#pragma unroll
        for (int i = 0; i < 16; ++i) {
            int row = i * 4 + r4;
            Ls[row][c] = W[(long)(k0 + row) * N + n0 + c];
        }
        __syncthreads();
#pragma unroll
        for (int i = 0; i < 16; ++i) {
            int row = i * 4 + r4; // n-local
            WT[(long)(n0 + row) * 512 + k0 + c] = (_Float16)Ls[c][row];
        }
    }
}

// ================= QKV GEMM: 256x256 tile, BK=64, 8-phase counted-vmcnt =================
// Q/K row-major fp16; V written TRANSPOSED via packed-b64 LDS transpose: VT[b][e][k].
__launch_bounds__(512, 2) __global__
void k_gemm_qkv(const _Float16* __restrict__ A, const _Float16* __restrict__ BT,
                const float* __restrict__ bias,
                _Float16* __restrict__ Qo, _Float16* __restrict__ Ko, _Float16* __restrict__ VT) {
    extern __shared__ __align__(16) char smem[];
    const int tid = threadIdx.x, w = tid >> 6, lane = tid & 63, g = lane >> 4, f = lane & 15;
    const int wrow = w >> 2, wcol = w & 3;
    const int bid = blockIdx.x;
    const int swz = (bid & 7) * 48 + (bid >> 3); // XCD swizzle, bijective (384 % 8 == 0)
    const int brow = swz / 6, bcol = swz - brow * 6;
    const long row0 = (long)brow * 256;
    const int col0 = bcol * 256;
    const char* Abase = (const char*)A + row0 * 1024;
    const char* Bbase = (const char*)BT + (long)col0 * 1024;

    f32x4 acc[8][4] = {};
    f16x8 a[4][2], b[2][2];

    auto stageA = [&](int h, char* dstbuf, int kt) {
#pragma unroll
        for (int it = 0; it < 2; ++it) {
            int s = it * 512 + tid;
            int lr = s >> 3;
            int ch = (s & 7) ^ (lr & 7);
            int r = (lr & 63) | ((lr & 64) << 1) | (h << 6);
            gl_lds16(Abase + (long)r * 1024 + kt * 128 + ch * 16, dstbuf + h * 16384 + s * 16);
        }
    };
    auto stageB = [&](int h, char* dstbuf, int kt) {
#pragma unroll
        for (int it = 0; it < 2; ++it) {
            int s = it * 512 + tid;
            int lr = s >> 3;
            int ch = (s & 7) ^ (lr & 7);
            int n = (lr & 31) | ((lr >> 5) << 6) | (h << 5);
            gl_lds16(Bbase + (long)n * 1024 + kt * 128 + ch * 16, dstbuf + h * 16384 + s * 16);
        }
    };
    auto ldA = [&](const char* buf, int mq) {
#pragma unroll
        for (int mi = 0; mi < 4; ++mi)
#pragma unroll
            for (int ks = 0; ks < 2; ++ks) {
                int r = wrow * 128 + mq * 64 + mi * 16 + f;
                int half = (r >> 6) & 1, lr = (r & 63) | ((r & 128) >> 1);
                int cl = ks * 4 + g;
                a[mi][ks] = *(const f16x8*)(buf + half * 16384 + lr * 128 + ((cl ^ (lr & 7)) << 4));
            }
    };
    auto ldB = [&](const char* buf, int nq) {
#pragma unroll
        for (int ni = 0; ni < 2; ++ni)
#pragma unroll
            for (int ks = 0; ks < 2; ++ks) {
                int n = wcol * 64 + nq * 32 + ni * 16 + f;
                int half = (n >> 5) & 1, lr = (n & 31) | (((n >> 6) & 3) << 5);
                int cl = ks * 4 + g;
                b[ni][ks] = *(const f16x8*)(buf + half * 16384 + lr * 128 + ((cl ^ (lr & 7)) << 4));
            }
    };
    auto mfma16 = [&](int mq, int nq) {
        __builtin_amdgcn_s_setprio(1);
#pragma unroll
        for (int mi = 0; mi < 4; ++mi)
#pragma unroll
            for (int ni = 0; ni < 2; ++ni)
#pragma unroll
                for (int ks = 0; ks < 2; ++ks)
                    acc[mq * 4 + mi][nq * 2 + ni] = MFMA(a[mi][ks], b[ni][ks], acc[mq * 4 + mi][nq * 2 + ni]);
        __builtin_amdgcn_s_setprio(0);
    };

    {
        char* A0 = smem;
        char* B0 = smem + 32768;
        stageA(0, A0, 0); stageB(0, B0, 0); stageB(1, B0, 0); stageA(1, A0, 0);
    }
    VMW(4);
    BARRIER();

    for (int kt = 0; kt < 8; ++kt) {
        const char* Ac = smem + (kt & 1) * 65536;
        const char* Bc = Ac + 32768;
        char* An = smem + ((kt + 1) & 1) * 65536;
        char* Bn = An + 32768;
        const bool last = (kt == 7);
        ldA(Ac, 0); ldB(Bc, 0);
        if (!last) stageA(0, An, kt + 1);
        BARRIER();
        mfma16(0, 0);
        if (!last) { VMW(4); } else { VMW(2); }
        BARRIER();
        ldB(Bc, 1);
        if (!last) stageB(0, Bn, kt + 1);
        BARRIER();
        mfma16(0, 1);
        if (!last) { VMW(4); } else { VMW(0); }
        BARRIER();
        ldA(Ac, 1); ldB(Bc, 0);
        if (!last) stageB(1, Bn, kt + 1);
        BARRIER();
        mfma16(1, 0);
        BARRIER();
        ldB(Bc, 1);
        if (!last) stageA(1, An, kt + 1);
        BARRIER();
        mfma16(1, 1);
        if (!last) { VMW(4); }
        BARRIER();
    }

    float bv[4];
#pragma unroll
    for (int ni = 0; ni < 4; ++ni) bv[ni] = bias[col0 + wcol * 64 + ni * 16 + f];

    if (col0 >= 1024) {
        // ---- V: packed transposed LDS write T[e][k], byte = e*512 + (k*2 ^ ((e&7)<<4)) ----
#pragma unroll
        for (int mi = 0; mi < 8; ++mi)
#pragma unroll
            for (int ni = 0; ni < 4; ++ni) {
                int r0 = wrow * 128 + mi * 16 + g * 4; // k index (4 consecutive j)
                int c = wcol * 64 + ni * 16 + f;       // e index
                f16x4 v4;
#pragma unroll
                for (int j = 0; j < 4; ++j) v4[j] = (_Float16)(acc[mi][ni][j] + bv[ni]);
                *(f16x4*)(smem + c * 512 + ((r0 * 2) ^ ((c & 7) << 4))) = v4;
            }
        __syncthreads();
        int bb = (int)(row0 >> 12);
        _Float16* vt = VT + ((long)bb * 512 + (col0 - 1024)) * 4096 + (row0 & 4095);
#pragma unroll
        for (int it = 0; it < 16; ++it) {
            int e = it * 16 + (tid >> 5);
            int ch = tid & 31;
            f16x8 v = *(const f16x8*)(smem + e * 512 + ((ch * 16) ^ ((e & 7) << 4)));
            *(f16x8*)(vt + (long)e * 4096 + ch * 8) = v;
        }
    } else {
        // ---- Q/K: rotation-swizzle row-major epilogue ----
        const float sc = (col0 < 512) ? QSCALE : 1.0f;
#pragma unroll
        for (int mi = 0; mi < 8; ++mi)
#pragma unroll
            for (int ni = 0; ni < 4; ++ni)
#pragma unroll
                for (int j = 0; j < 4; ++j) {
                    int r = wrow * 128 + mi * 16 + g * 4 + j;
                    int c = wcol * 64 + ni * 16 + f;
                    float v = (acc[mi][ni][j] + bv[ni]) * sc;
                    int pc = ((c >> 3) + ((r >> 2) & 7) * 2) & 31;
                    *(_Float16*)(smem + r * 512 + pc * 16 + (c & 7) * 2) = (_Float16)v;
                }
        __syncthreads();
        _Float16* dst = (col0 < 512) ? Qo : Ko;
        int cofs = (col0 < 512) ? col0 : col0 - 512;
#pragma unroll
        for (int it = 0; it < 16; ++it) {
            int r = it * 16 + (tid >> 5);
            int ch = tid & 31;
            int pc = (ch + ((r >> 2) & 7) * 2) & 31;
            f16x8 v = *(const f16x8*)(smem + r * 512 + pc * 16);
            *(f16x8*)(dst + (row0 + r) * 512 + cofs + ch * 8) = v;
        }
    }
}

// ================= out-projection GEMM (m97-style 128x128) =================
__launch_bounds__(256, 2) __global__
void k_gemm_out(const _Float16* __restrict__ A, const _Float16* __restrict__ BT,
                const float* __restrict__ bias, float* __restrict__ out) {
    __shared__ __align__(16) _Float16 As[128 * 64];
    __shared__ __align__(16) _Float16 Bs[128 * 64];
    const int tid = threadIdx.x, w = tid >> 6, lane = tid & 63, g = lane >> 4, f = lane & 15;
    const int wr = w >> 1, wc = w & 1;
    const long row0 = (long)blockIdx.x * 128, col0 = (long)blockIdx.y * 128;
    f32x4 acc[4][4] = {};
    const char* Ab = (const char*)(A + row0 * 512);
    const char* Bb = (const char*)(BT + col0 * 512);

    for (int kt = 0; kt < 8; ++kt) {
        __syncthreads();
        const char* Asrc = Ab + kt * 128;
        const char* Bsrc = Bb + kt * 128;
#pragma unroll
        for (int it = 0; it < 4; ++it) {
            int slot = it * 256 + tid;
            int r = slot >> 3, ch = slot & 7;
            int scol = (ch * 16) ^ ((r & 7) << 4);
            gl_lds16(Asrc + (long)r * 1024 + scol, (char*)As + (it * 256 + (tid & 0xC0)) * 16);
            gl_lds16(Bsrc + (long)r * 1024 + scol, (char*)Bs + (it * 256 + (tid & 0xC0)) * 16);
        }
        __syncthreads();
#pragma unroll
        for (int ks = 0; ks < 2; ++ks) {
            f16x8 af[4], bf[4];
#pragma unroll
            for (int mi = 0; mi < 4; ++mi) {
                int r = wr * 64 + mi * 16 + f;
                af[mi] = *(const f16x8*)((const char*)As + r * 128 + ((ks * 64 + g * 16) ^ ((r & 7) << 4)));
            }
#pragma unroll
            for (int ni = 0; ni < 4; ++ni) {
                int r = wc * 64 + ni * 16 + f;
                bf[ni] = *(const f16x8*)((const char*)Bs + r * 128 + ((ks * 64 + g * 16) ^ ((r & 7) << 4)));
            }
#pragma unroll
            for (int mi = 0; mi < 4; ++mi)
#pragma unroll
                for (int ni = 0; ni < 4; ++ni)
                    acc[mi][ni] = MFMA(af[mi], bf[ni], acc[mi][ni]);
        }
    }
#pragma unroll
    for (int mi = 0; mi < 4; ++mi)
#pragma unroll
        for (int ni = 0; ni < 4; ++ni) {
            long r0 = row0 + wr * 64 + mi * 16 + g * 4;
            int c = (int)col0 + wc * 64 + ni * 16 + f;
            float bv = bias[c];
#pragma unroll
            for (int j = 0; j < 4; ++j)
                out[(r0 + j) * 512 + c] = acc[mi][ni][j] + bv;
        }
}

// ================= windowed attention: QBLK=64, 512 thr, LDS-staged K & VT =================
// 8 waves: rh = w>>2 (32-row half), kh = w&3 (48-key quarter for QK^T; 32-e quarter for PV).
// LDS: 2 x 48KB stage buffers (K: [192][128e], VT: [128e][192k], XOR-swizzled) + P + Mp/Lp.
__launch_bounds__(512, 1) __global__
void k_attn(const _Float16* __restrict__ Qb, const _Float16* __restrict__ Kb,
            const _Float16* __restrict__ VT, _Float16* __restrict__ Ob) {
    extern __shared__ __align__(16) char smem[];
    char* buf[2] = { smem, smem + 49152 };
    char* Pl = smem + 98304;                 // 64 rows x 400B = 25600
    float* Mp = (float*)(smem + 123904);     // [4][64]
    float* Lp = (float*)(smem + 124928);     // [4][64]

    const int tid = threadIdx.x, w = tid >> 6, lane = tid & 63, g = lane >> 4, f = lane & 15;
    const int rh = w >> 2, kh = w & 3;
    const int bid = blockIdx.x;
    const int swzb = (bid & 7) * 32 + (bid >> 3); // XCD swizzle (256 % 8 == 0)
    const int b = swzb >> 6, qt = swzb & 63;
    const int q0 = qt * 64, kbase = q0 - 64; // 192-key span
    const long bofs = (long)b * SEQ;

    // ---- Q fragments: 32 rows x full E in registers ----
    f16x8 qf[2][16];
#pragma unroll
    for (int mt = 0; mt < 2; ++mt) {
        const _Float16* qr = Qb + (bofs + q0 + rh * 32 + mt * 16 + f) * EMB + g * 8;
#pragma unroll
        for (int ks = 0; ks < 16; ++ks) qf[mt][ks] = *(const f16x8*)(qr + ks * 32);
    }

    auto stageK = [&](int ec, char* dst) {
#pragma unroll
        for (int it = 0; it < 6; ++it) {
            int slot = it * 512 + tid;
            int r = slot >> 4, c = slot & 15;
            int cs = c ^ (r & 7);
            int key = min(max(kbase + r, 0), SEQ - 1);
            gl_lds16(Kb + (bofs + key) * EMB + ec * 128 + cs * 8, dst + slot * 16);
        }
    };
    auto stageVT = [&](int ec, char* dst) {
#pragma unroll
        for (int it = 0; it < 6; ++it) {
            int slot = it * 512 + tid;
            int r = slot / 24, c = slot - r * 24;
            int cs = c ^ (r & 7);
            int k0 = min(max(kbase + cs * 8, 0), SEQ - 8);
            gl_lds16(VT + ((long)b * 512 + ec * 128 + r) * 4096 + k0, dst + slot * 16);
        }
    };

    // ================= QK^T over 4 e-chunks =================
    f32x4 sacc[2][3] = {};
    stageK(0, buf[0]);
    __syncthreads();
    for (int ec = 0; ec < 4; ++ec) {
        if (ec < 3) stageK(ec + 1, buf[(ec + 1) & 1]);
        else stageVT(0, buf[0]); // buf0 free after ec=2's barrier
        const char* kb = buf[ec & 1];
#pragma unroll
        for (int kk = 0; kk < 4; ++kk) {
#pragma unroll
            for (int t = 0; t < 3; ++t) {
                int n = kh * 48 + t * 16 + f;
                f16x8 bf = *(const f16x8*)(kb + n * 256 + (((kk * 4 + g) ^ (n & 7)) << 4));
#pragma unroll
                for (int mt = 0; mt < 2; ++mt)
                    sacc[mt][t] = MFMA(qf[mt][ec * 4 + kk], bf, sacc[mt][t]);
            }
        }
        __syncthreads();
    }

    // ================= mask + 4-way softmax =================
    float m[2][4] = {{-3e30f, -3e30f, -3e30f, -3e30f}, {-3e30f, -3e30f, -3e30f, -3e30f}};
    float l[2][4] = {};
#pragma unroll
    for (int mt = 0; mt < 2; ++mt)
#pragma unroll
        for (int t = 0; t < 3; ++t) {
            int key = kbase + kh * 48 + t * 16 + f;
            bool kv = (key >= 0) && (key < SEQ);
#pragma unroll
            for (int j = 0; j < 4; ++j) {
                int d = key - (q0 + rh * 32 + mt * 16 + g * 4 + j);
                bool valid = kv && (d >= -64) && (d <= 64);
                float s = valid ? sacc[mt][t][j] : -3e30f;
                sacc[mt][t][j] = s;
                m[mt][j] = fmaxf(m[mt][j], s);
            }
        }
#pragma unroll
    for (int mt = 0; mt < 2; ++mt)
#pragma unroll
        for (int j = 0; j < 4; ++j) {
            m[mt][j] = fmaxf(m[mt][j], __shfl_xor(m[mt][j], 1));
            m[mt][j] = fmaxf(m[mt][j], __shfl_xor(m[mt][j], 2));
            m[mt][j] = fmaxf(m[mt][j], __shfl_xor(m[mt][j], 4));
            m[mt][j] = fmaxf(m[mt][j], __shfl_xor(m[mt][j], 8));
        }
    if (f == 0) {
#pragma unroll
        for (int mt = 0; mt < 2; ++mt)
#pragma unroll
            for (int j = 0; j < 4; ++j)
                Mp[kh * 64 + rh * 32 + mt * 16 + g * 4 + j] = m[mt][j];
    }
    __syncthreads();
#pragma unroll
    for (int mt = 0; mt < 2; ++mt)
#pragma unroll
        for (int j = 0; j < 4; ++j) {
            int r = rh * 32 + mt * 16 + g * 4 + j;
            m[mt][j] = fmaxf(fmaxf(Mp[r], Mp[64 + r]), fmaxf(Mp[128 + r], Mp[192 + r]));
        }
#pragma unroll
    for (int mt = 0; mt < 2; ++mt)
#pragma unroll
        for (int t = 0; t < 3; ++t)
#pragma unroll
            for (int j = 0; j < 4; ++j) {
                float p = __expf(sacc[mt][t][j] - m[mt][j]);
                sacc[mt][t][j] = p;
                l[mt][j] += p;
            }
#pragma unroll
    for (int mt = 0; mt < 2; ++mt)
#pragma unroll
        for (int j = 0; j < 4; ++j) {
            l[mt][j] += __shfl_xor(l[mt][j], 1);
            l[mt][j] += __shfl_xor(l[mt][j], 2);
            l[mt][j] += __shfl_xor(l[mt][j], 4);
            l[mt][j] += __shfl_xor(l[mt][j], 8);
        }
    if (f == 0) {
#pragma unroll
        for (int mt = 0; mt < 2; ++mt)
#pragma unroll
            for (int j = 0; j < 4; ++j)
                Lp[kh * 64 + rh * 32 + mt * 16 + g * 4 + j] = l[mt][j];
    }
    // P -> LDS fp16
#pragma unroll
    for (int mt = 0; mt < 2; ++mt)
#pragma unroll
        for (int t = 0; t < 3; ++t)
#pragma unroll
            for (int j = 0; j < 4; ++j)
                *(_Float16*)(Pl + (rh * 32 + mt * 16 + g * 4 + j) * 400 +
                             (kh * 48 + t * 16 + f) * 2) = (_Float16)sacc[mt][t][j];
    __syncthreads(); // P + Lp ready; VT chunk 0 drained (vmcnt 0 in syncthreads)

    float rl[2][4];
#pragma unroll
    for (int mt = 0; mt < 2; ++mt)
#pragma unroll
        for (int j = 0; j < 4; ++j) {
            int r = rh * 32 + mt * 16 + g * 4 + j;
            rl[mt][j] = 1.0f / (Lp[r] + Lp[64 + r] + Lp[128 + r] + Lp[192 + r]);
        }

    // P fragments (A operand): 32 rows x 192 keys
    f16x8 pf[2][6];
#pragma unroll
    for (int mt = 0; mt < 2; ++mt)
#pragma unroll
        for (int kc = 0; kc < 6; ++kc)
            pf[mt][kc] = *(const f16x8*)(Pl + (rh * 32 + mt * 16 + f) * 400 + kc * 64 + g * 16);

    // ================= PV over 4 e-chunks =================
    for (int ec = 0; ec < 4; ++ec) {
        if (ec < 3) stageVT(ec + 1, buf[(ec + 1) & 1]);
        const char* vb = buf[ec & 1];
        f32x4 o[2][2] = {};
#pragma unroll
        for (int kc = 0; kc < 6; ++kc) {
#pragma unroll
            for (int nt = 0; nt < 2; ++nt) {
                int e = kh * 32 + nt * 16 + f;
                f16x8 vf = *(const f16x8*)(vb + e * 384 + (((kc * 4 + g) ^ (e & 7)) << 4));
#pragma unroll
                for (int mt = 0; mt < 2; ++mt)
                    o[mt][nt] = MFMA(pf[mt][kc], vf, o[mt][nt]);
            }
        }
#pragma unroll
        for (int mt = 0; mt < 2; ++mt)
#pragma unroll
            for (int nt = 0; nt < 2; ++nt) {
                _Float16* ob = Ob + (bofs + q0 + rh * 32 + mt * 16 + g * 4) * EMB +
                               ec * 128 + kh * 32 + nt * 16 + f;
#pragma unroll
                for (int j = 0; j < 4; ++j)
                    ob[(long)j * EMB] = (_Float16)(o[mt][nt][j] * rl[mt][j]);
            }
        if (ec < 3) __syncthreads();
    }
}

extern "C" void kernel_launch(void* const* d_in, const int* in_sizes, int n_in,
                              void* d_out, int out_size, void* d_ws, size_t ws_size,
                              hipStream_t stream) {
    const float* x     = (const float*)d_in[0];
    const float* W_qkv = (const float*)d_in[1];
    const float* b_qkv = (const float*)d_in[2];
    const float* W_out = (const float*)d_in[3];
    const float* b_out = (const float*)d_in[4];

    char* ws = (char*)d_ws;
    _Float16* xb    = (_Float16*)(ws);                         // 16 MiB
    _Float16* WqkvT = (_Float16*)(ws + 16777216);              // 1.5 MiB
    _Float16* WoutT = (_Float16*)(ws + 16777216 + 1572864);    // 0.5 MiB
    _Float16* Qb    = (_Float16*)(ws + 18874368);              // 16 MiB
    _Float16* Kb    = (_Float16*)(ws + 18874368 + 16777216);   // 16 MiB
    _Float16* VT    = (_Float16*)(ws + 18874368 + 33554432);   // 16 MiB [b][e][k]
    _Float16* Ob    = xb; // reuse xb (dead after QKV GEMM)
    float* out = (float*)d_out;

    (void)hipFuncSetAttribute((const void*)k_gemm_qkv,
                              hipFuncAttributeMaxDynamicSharedMemorySize, 131072);
    (void)hipFuncSetAttribute((const void*)k_attn,
                              hipFuncAttributeMaxDynamicSharedMemorySize, 126976);

    k_prep<<<4352, 256, 0, stream>>>(x, xb, W_qkv, WqkvT, W_out, WoutT);
    k_gemm_qkv<<<384, 512, 131072, stream>>>(xb, WqkvT, b_qkv, Qb, Kb, VT);
    k_attn<<<256, 512, 125952, stream>>>(Qb, Kb, VT, Ob);
    dim3 g2(128, 4);
    k_gemm_out<<<g2, 256, 0, stream>>>(Ob, WoutT, b_out, out);
}

// Round 6
// 82.426 us; speedup vs baseline: 1.5232x; 1.0629x over previous
//
#include <hip/hip_runtime.h>

typedef __attribute__((ext_vector_type(8))) _Float16 f16x8;
typedef __attribute__((ext_vector_type(4))) _Float16 f16x4;
typedef __attribute__((ext_vector_type(4))) float f32x4;
typedef __attribute__((address_space(1))) const char gc_char;
typedef __attribute__((address_space(3))) char ls_char;

#define MFMA(a, b, c) __builtin_amdgcn_mfma_f32_16x16x32_f16((a), (b), (c), 0, 0, 0)
#define FENCE() asm volatile("" ::: "memory")
#define BARRIER() do { FENCE(); __builtin_amdgcn_s_barrier(); FENCE(); } while (0)
#define VMW(n) asm volatile("s_waitcnt vmcnt(" #n ")" ::: "memory")

static constexpr int SEQ = 4096;
static constexpr int EMB = 512;
static constexpr float QSCALE = 0.04419417382415922f; // 1/sqrt(512)

__device__ __forceinline__ void gl_lds16(const void* g, void* l) {
    __builtin_amdgcn_global_load_lds((gc_char*)g, (ls_char*)l, 16, 0, 0);
}

// ---------------- fused prep: cast x + LDS-tiled transpose-cast both W ----------------
__global__ void k_prep(const float* __restrict__ x, _Float16* __restrict__ xb,
                       const float* __restrict__ Wq, _Float16* __restrict__ WqT,
                       const float* __restrict__ Wo, _Float16* __restrict__ WoT) {
    const int bid = blockIdx.x, tid = threadIdx.x;
    if (bid < 4096) {
        long i = (long)bid * 256 + tid;
        const float4* p = (const float4*)x + i * 2;
        float4 a = p[0], b = p[1];
        f16x8 v;
        v[0] = (_Float16)a.x; v[1] = (_Float16)a.y; v[2] = (_Float16)a.z; v[3] = (_Float16)a.w;
        v[4] = (_Float16)b.x; v[5] = (_Float16)b.y; v[6] = (_Float16)b.z; v[7] = (_Float16)b.w;
        *(f16x8*)(xb + i * 8) = v;
    } else {
        __shared__ float Ls[64][65];
        int t = bid - 4096;
        const float* W; _Float16* WT; int N, k0, n0;
        if (t < 192) { W = Wq; WT = WqT; N = 1536; k0 = (t & 7) * 64; n0 = (t >> 3) * 64; }
        else { t -= 192; W = Wo; WT = WoT; N = 512; k0 = (t & 7) * 64; n0 = (t >> 3) * 64; }
        int c = tid & 63, r4 = tid >> 6;
#pragma unroll
        for (int i = 0; i < 16; ++i) {
            int row = i * 4 + r4;
            Ls[row][c] = W[(long)(k0 + row) * N + n0 + c];
        }
        __syncthreads();
#pragma unroll
        for (int i = 0; i < 16; ++i) {
            int row = i * 4 + r4;
            WT[(long)(n0 + row) * 512 + k0 + c] = (_Float16)Ls[c][row];
        }
    }
}

// ================= 128x256 tile, BK=64, 4-phase counted-vmcnt GEMM template =================
// 512 thr = 8 waves (2M x 4N), per-wave 64x64. B fragments register-resident per K-tile.
// LDS per dbuf half (48KB): A0 8KB | A1 8KB | B0 16KB | B1 16KB. Stage units (1 load/thr each):
// per K-tile: B0'(2u)@p0, A0'+A1'(2u)@p1, B1'(2u)@p2. Waits: p0 VMW(2), boundary VMW(3).
// EPI 0: QKV split (Q scaled, V transposed to VT[b][e][k]).  EPI 1: fp32 + bias.
template <int NCT, int EPI>
__launch_bounds__(512, 1) __global__
void k_gemm2(const _Float16* __restrict__ A, const _Float16* __restrict__ BT,
             const float* __restrict__ bias, void* o0, void* o1, void* o2) {
    extern __shared__ __align__(16) char smem[];
    const int tid = threadIdx.x, lane = tid & 63, w = tid >> 6, g = lane >> 4, f = lane & 15;
    const int wrow = w >> 2, wcol = w & 3;
    const int bid = blockIdx.x;
    constexpr int NBLK = 128 * NCT;
    const int swz = (bid & 7) * (NBLK / 8) + (bid >> 3); // bijective XCD swizzle
    const int brow = swz / NCT, bcol = swz - brow * NCT;
    const long row0 = (long)brow * 128;
    const int col0 = bcol * 256;
    const char* Abase = (const char*)A + row0 * 1024;
    const char* Bbase = (const char*)BT + (long)col0 * 1024;

    f32x4 acc[4][4] = {};
    f16x8 a[2][2], breg[2][2][2];

    auto stageA = [&](int h, char* dst, int kt) {
        int rr = tid >> 3;
        int ch = (tid & 7) ^ (rr & 7);
        int grow = h * 32 + (rr & 31) + (rr >> 5) * 64;
        gl_lds16(Abase + (long)grow * 1024 + kt * 128 + ch * 16, dst + h * 8192 + tid * 16);
    };
    auto stageB = [&](int h, char* dst, int kt) {
#pragma unroll
        for (int it = 0; it < 2; ++it) {
            int s = it * 512 + tid;
            int cc = s >> 3;
            int ch = (s & 7) ^ (cc & 7);
            int gcol = h * 32 + (cc & 31) + (cc >> 5) * 64;
            gl_lds16(Bbase + (long)gcol * 1024 + kt * 128 + ch * 16,
                     dst + 16384 + h * 16384 + s * 16);
        }
    };
    auto ldA = [&](const char* buf, int mh) {
#pragma unroll
        for (int mi = 0; mi < 2; ++mi)
#pragma unroll
            for (int ks = 0; ks < 2; ++ks) {
                int rr = wrow * 32 + mi * 16 + f;
                int cl = ks * 4 + g;
                a[mi][ks] = *(const f16x8*)(buf + mh * 8192 + rr * 128 + ((cl ^ (rr & 7)) << 4));
            }
    };
    auto ldB = [&](const char* buf, int nh) {
#pragma unroll
        for (int ni = 0; ni < 2; ++ni)
#pragma unroll
            for (int ks = 0; ks < 2; ++ks) {
                int cc = wcol * 32 + ni * 16 + f;
                int cl = ks * 4 + g;
                breg[nh][ni][ks] =
                    *(const f16x8*)(buf + 16384 + nh * 16384 + cc * 128 + ((cl ^ (cc & 7)) << 4));
            }
    };
    auto mfma8 = [&](int mh, int nh) {
        __builtin_amdgcn_s_setprio(1);
#pragma unroll
        for (int mi = 0; mi < 2; ++mi)
#pragma unroll
            for (int ni = 0; ni < 2; ++ni)
#pragma unroll
                for (int ks = 0; ks < 2; ++ks)
                    acc[mh * 2 + mi][nh * 2 + ni] =
                        MFMA(a[mi][ks], breg[nh][ni][ks], acc[mh * 2 + mi][nh * 2 + ni]);
        __builtin_amdgcn_s_setprio(0);
    };

    // prologue: tile 0 into buf0, order B0(2),A0,A1,B1(2); keep A1,B1 in flight
    stageB(0, smem, 0);
    stageA(0, smem, 0); stageA(1, smem, 0);
    stageB(1, smem, 0);
    VMW(3);
    BARRIER();

    for (int kt = 0; kt < 8; ++kt) {
        const char* cur = smem + (kt & 1) * 49152;
        char* nxt = smem + ((kt + 1) & 1) * 49152;
        const bool last = (kt == 7);
        // p0: (m0,n0); stage B0'
        ldA(cur, 0); ldB(cur, 0);
        if (!last) stageB(0, nxt, kt + 1);
        BARRIER();
        mfma8(0, 0);
        if (!last) { VMW(2); } else { VMW(0); } // retire A1,B1 of current tile
        BARRIER();
        // p1: (m0,n1); stage A0',A1'
        ldB(cur, 1);
        if (!last) { stageA(0, nxt, kt + 1); stageA(1, nxt, kt + 1); }
        BARRIER();
        mfma8(0, 1);
        BARRIER();
        // p2: (m1,n0); stage B1'
        ldA(cur, 1);
        if (!last) stageB(1, nxt, kt + 1);
        BARRIER();
        mfma8(1, 0);
        BARRIER();
        // p3: (m1,n1) pure-reg
        mfma8(1, 1);
        if (!last) { VMW(3); } // boundary: retire B0',A0'
        BARRIER();
    }

    // ================= epilogue =================
    if (EPI == 1) {
        float* out = (float*)o0;
#pragma unroll
        for (int mi = 0; mi < 4; ++mi)
#pragma unroll
            for (int ni = 0; ni < 4; ++ni) {
                long r0 = row0 + wrow * 64 + mi * 16 + g * 4;
                int c = col0 + wcol * 64 + ni * 16 + f;
                float bv = bias[c];
#pragma unroll
                for (int j = 0; j < 4; ++j)
                    out[(r0 + j) * 512 + c] = acc[mi][ni][j] + bv;
            }
        return;
    }

    float bv[4];
#pragma unroll
    for (int ni = 0; ni < 4; ++ni) bv[ni] = bias[col0 + wcol * 64 + ni * 16 + f];

    if (col0 >= 1024) {
        // V: packed transposed LDS T[e][k], byte = e*256 + ((k*2) ^ ((e&7)<<4))
#pragma unroll
        for (int mi = 0; mi < 4; ++mi)
#pragma unroll
            for (int ni = 0; ni < 4; ++ni) {
                int r0 = wrow * 64 + mi * 16 + g * 4; // k (4 consecutive j)
                int c = wcol * 64 + ni * 16 + f;      // e
                f16x4 v4;
#pragma unroll
                for (int j = 0; j < 4; ++j) v4[j] = (_Float16)(acc[mi][ni][j] + bv[ni]);
                *(f16x4*)(smem + c * 256 + ((r0 * 2) ^ ((c & 7) << 4))) = v4;
            }
        __syncthreads();
        int bb = (int)(row0 >> 12);
        _Float16* vt = (_Float16*)o2 + ((long)bb * 512 + (col0 - 1024)) * 4096 + (row0 & 4095);
#pragma unroll
        for (int it = 0; it < 8; ++it) {
            int slot = it * 512 + tid;
            int e = slot >> 4, ch = slot & 15;
            f16x8 v = *(const f16x8*)(smem + e * 256 + ((ch * 16) ^ ((e & 7) << 4)));
            *(f16x8*)(vt + (long)e * 4096 + ch * 8) = v;
        }
    } else {
        // Q/K: rotation-swizzle row-major
        const float sc = (col0 < 512) ? QSCALE : 1.0f;
#pragma unroll
        for (int mi = 0; mi < 4; ++mi)
#pragma unroll
            for (int ni = 0; ni < 4; ++ni)
#pragma unroll
                for (int j = 0; j < 4; ++j) {
                    int r = wrow * 64 + mi * 16 + g * 4 + j;
                    int c = wcol * 64 + ni * 16 + f;
                    float v = (acc[mi][ni][j] + bv[ni]) * sc;
                    int pc = ((c >> 3) + ((r >> 2) & 7) * 2) & 31;
                    *(_Float16*)(smem + r * 512 + pc * 16 + (c & 7) * 2) = (_Float16)v;
                }
        __syncthreads();
        _Float16* dst = (col0 < 512) ? (_Float16*)o0 : (_Float16*)o1;
        int cofs = (col0 < 512) ? col0 : col0 - 512;
#pragma unroll
        for (int it = 0; it < 8; ++it) {
            int slot = it * 512 + tid;
            int r = slot >> 5, ch = slot & 31;
            int pc = (ch + ((r >> 2) & 7) * 2) & 31;
            f16x8 v = *(const f16x8*)(smem + r * 512 + pc * 16);
            *(f16x8*)(dst + (row0 + r) * 512 + cofs + ch * 8) = v;
        }
    }
}

// ================= windowed attention: QBLK=64, 512 thr, LDS-staged K & VT =================
__launch_bounds__(512, 1) __global__
void k_attn(const _Float16* __restrict__ Qb, const _Float16* __restrict__ Kb,
            const _Float16* __restrict__ VT, _Float16* __restrict__ Ob) {
    extern __shared__ __align__(16) char smem[];
    char* buf[2] = { smem, smem + 49152 };
    char* Pl = smem + 98304;
    float* Mp = (float*)(smem + 123904);
    float* Lp = (float*)(smem + 124928);

    const int tid = threadIdx.x, w = tid >> 6, lane = tid & 63, g = lane >> 4, f = lane & 15;
    const int rh = w >> 2, kh = w & 3;
    const int bid = blockIdx.x;
    const int swzb = (bid & 7) * 32 + (bid >> 3);
    const int b = swzb >> 6, qt = swzb & 63;
    const int q0 = qt * 64, kbase = q0 - 64;
    const long bofs = (long)b * SEQ;

    f16x8 qf[2][16];
#pragma unroll
    for (int mt = 0; mt < 2; ++mt) {
        const _Float16* qr = Qb + (bofs + q0 + rh * 32 + mt * 16 + f) * EMB + g * 8;
#pragma unroll
        for (int ks = 0; ks < 16; ++ks) qf[mt][ks] = *(const f16x8*)(qr + ks * 32);
    }

    auto stageK = [&](int ec, char* dst) {
#pragma unroll
        for (int it = 0; it < 6; ++it) {
            int slot = it * 512 + tid;
            int r = slot >> 4, c = slot & 15;
            int cs = c ^ (r & 7);
            int key = min(max(kbase + r, 0), SEQ - 1);
            gl_lds16(Kb + (bofs + key) * EMB + ec * 128 + cs * 8, dst + slot * 16);
        }
    };
    auto stageVT = [&](int ec, char* dst) {
#pragma unroll
        for (int it = 0; it < 6; ++it) {
            int slot = it * 512 + tid;
            int r = slot / 24, c = slot - r * 24;
            int cs = c ^ (r & 7);
            int k0 = min(max(kbase + cs * 8, 0), SEQ - 8);
            gl_lds16(VT + ((long)b * 512 + ec * 128 + r) * 4096 + k0, dst + slot * 16);
        }
    };

    f32x4 sacc[2][3] = {};
    stageK(0, buf[0]);
    __syncthreads();
    for (int ec = 0; ec < 4; ++ec) {
        if (ec < 3) stageK(ec + 1, buf[(ec + 1) & 1]);
        else stageVT(0, buf[0]);
        const char* kb = buf[ec & 1];
#pragma unroll
        for (int kk = 0; kk < 4; ++kk) {
#pragma unroll
            for (int t = 0; t < 3; ++t) {
                int n = kh * 48 + t * 16 + f;
                f16x8 bf = *(const f16x8*)(kb + n * 256 + (((kk * 4 + g) ^ (n & 7)) << 4));
#pragma unroll
                for (int mt = 0; mt < 2; ++mt)
                    sacc[mt][t] = MFMA(qf[mt][ec * 4 + kk], bf, sacc[mt][t]);
            }
        }
        __syncthreads();
    }

    float m[2][4] = {{-3e30f, -3e30f, -3e30f, -3e30f}, {-3e30f, -3e30f, -3e30f, -3e30f}};
    float l[2][4] = {};
#pragma unroll
    for (int mt = 0; mt < 2; ++mt)
#pragma unroll
        for (int t = 0; t < 3; ++t) {
            int key = kbase + kh * 48 + t * 16 + f;
            bool kv = (key >= 0) && (key < SEQ);
#pragma unroll
            for (int j = 0; j < 4; ++j) {
                int d = key - (q0 + rh * 32 + mt * 16 + g * 4 + j);
                bool valid = kv && (d >= -64) && (d <= 64);
                float s = valid ? sacc[mt][t][j] : -3e30f;
                sacc[mt][t][j] = s;
                m[mt][j] = fmaxf(m[mt][j], s);
            }
        }
#pragma unroll
    for (int mt = 0; mt < 2; ++mt)
#pragma unroll
        for (int j = 0; j < 4; ++j) {
            m[mt][j] = fmaxf(m[mt][j], __shfl_xor(m[mt][j], 1));
            m[mt][j] = fmaxf(m[mt][j], __shfl_xor(m[mt][j], 2));
            m[mt][j] = fmaxf(m[mt][j], __shfl_xor(m[mt][j], 4));
            m[mt][j] = fmaxf(m[mt][j], __shfl_xor(m[mt][j], 8));
        }
    if (f == 0) {
#pragma unroll
        for (int mt = 0; mt < 2; ++mt)
#pragma unroll
            for (int j = 0; j < 4; ++j)
                Mp[kh * 64 + rh * 32 + mt * 16 + g * 4 + j] = m[mt][j];
    }
    __syncthreads();
#pragma unroll
    for (int mt = 0; mt < 2; ++mt)
#pragma unroll
        for (int j = 0; j < 4; ++j) {
            int r = rh * 32 + mt * 16 + g * 4 + j;
            m[mt][j] = fmaxf(fmaxf(Mp[r], Mp[64 + r]), fmaxf(Mp[128 + r], Mp[192 + r]));
        }
#pragma unroll
    for (int mt = 0; mt < 2; ++mt)
#pragma unroll
        for (int t = 0; t < 3; ++t)
#pragma unroll
            for (int j = 0; j < 4; ++j) {
                float p = __expf(sacc[mt][t][j] - m[mt][j]);
                sacc[mt][t][j] = p;
                l[mt][j] += p;
            }
#pragma unroll
    for (int mt = 0; mt < 2; ++mt)
#pragma unroll
        for (int j = 0; j < 4; ++j) {
            l[mt][j] += __shfl_xor(l[mt][j], 1);
            l[mt][j] += __shfl_xor(l[mt][j], 2);
            l[mt][j] += __shfl_xor(l[mt][j], 4);
            l[mt][j] += __shfl_xor(l[mt][j], 8);
        }
    if (f == 0) {
#pragma unroll
        for (int mt = 0; mt < 2; ++mt)
#pragma unroll
            for (int j = 0; j < 4; ++j)
                Lp[kh * 64 + rh * 32 + mt * 16 + g * 4 + j] = l[mt][j];
    }
#pragma unroll
    for (int mt = 0; mt < 2; ++mt)
#pragma unroll
        for (int t = 0; t < 3; ++t)
#pragma unroll
            for (int j = 0; j < 4; ++j)
                *(_Float16*)(Pl + (rh * 32 + mt * 16 + g * 4 + j) * 400 +
                             (kh * 48 + t * 16 + f) * 2) = (_Float16)sacc[mt][t][j];
    __syncthreads();

    float rl[2][4];
#pragma unroll
    for (int mt = 0; mt < 2; ++mt)
#pragma unroll
        for (int j = 0; j < 4; ++j) {
            int r = rh * 32 + mt * 16 + g * 4 + j;
            rl[mt][j] = 1.0f / (Lp[r] + Lp[64 + r] + Lp[128 + r] + Lp[192 + r]);
        }

    f16x8 pf[2][6];
#pragma unroll
    for (int mt = 0; mt < 2; ++mt)
#pragma unroll
        for (int kc = 0; kc < 6; ++kc)
            pf[mt][kc] = *(const f16x8*)(Pl + (rh * 32 + mt * 16 + f) * 400 + kc * 64 + g * 16);

    for (int ec = 0; ec < 4; ++ec) {
        if (ec < 3) stageVT(ec + 1, buf[(ec + 1) & 1]);
        const char* vb = buf[ec & 1];
        f32x4 o[2][2] = {};
#pragma unroll
        for (int kc = 0; kc < 6; ++kc) {
#pragma unroll
            for (int nt = 0; nt < 2; ++nt) {
                int e = kh * 32 + nt * 16 + f;
                f16x8 vf = *(const f16x8*)(vb + e * 384 + (((kc * 4 + g) ^ (e & 7)) << 4));
#pragma unroll
                for (int mt = 0; mt < 2; ++mt)
                    o[mt][nt] = MFMA(pf[mt][kc], vf, o[mt][nt]);
            }
        }
#pragma unroll
        for (int mt = 0; mt < 2; ++mt)
#pragma unroll
            for (int nt = 0; nt < 2; ++nt) {
                _Float16* ob = Ob + (bofs + q0 + rh * 32 + mt * 16 + g * 4) * EMB +
                               ec * 128 + kh * 32 + nt * 16 + f;
#pragma unroll
                for (int j = 0; j < 4; ++j)
                    ob[(long)j * EMB] = (_Float16)(o[mt][nt][j] * rl[mt][j]);
            }
        if (ec < 3) __syncthreads();
    }
}

extern "C" void kernel_launch(void* const* d_in, const int* in_sizes, int n_in,
                              void* d_out, int out_size, void* d_ws, size_t ws_size,
                              hipStream_t stream) {
    const float* x     = (const float*)d_in[0];
    const float* W_qkv = (const float*)d_in[1];
    const float* b_qkv = (const float*)d_in[2];
    const float* W_out = (const float*)d_in[3];
    const float* b_out = (const float*)d_in[4];

    char* ws = (char*)d_ws;
    _Float16* xb    = (_Float16*)(ws);                         // 16 MiB
    _Float16* WqkvT = (_Float16*)(ws + 16777216);              // 1.5 MiB
    _Float16* WoutT = (_Float16*)(ws + 16777216 + 1572864);    // 0.5 MiB
    _Float16* Qb    = (_Float16*)(ws + 18874368);              // 16 MiB
    _Float16* Kb    = (_Float16*)(ws + 18874368 + 16777216);   // 16 MiB
    _Float16* VT    = (_Float16*)(ws + 18874368 + 33554432);   // 16 MiB [b][e][k]
    _Float16* Ob    = xb; // reuse xb (dead after QKV GEMM)
    float* out = (float*)d_out;

    (void)hipFuncSetAttribute((const void*)k_gemm2<6, 0>,
                              hipFuncAttributeMaxDynamicSharedMemorySize, 98304);
    (void)hipFuncSetAttribute((const void*)k_gemm2<2, 1>,
                              hipFuncAttributeMaxDynamicSharedMemorySize, 98304);
    (void)hipFuncSetAttribute((const void*)k_attn,
                              hipFuncAttributeMaxDynamicSharedMemorySize, 126976);

    k_prep<<<4352, 256, 0, stream>>>(x, xb, W_qkv, WqkvT, W_out, WoutT);
    k_gemm2<6, 0><<<768, 512, 98304, stream>>>(xb, WqkvT, b_qkv, Qb, Kb, VT);
    k_attn<<<256, 512, 125952, stream>>>(Qb, Kb, VT, Ob);
    k_gemm2<2, 1><<<256, 512, 98304, stream>>>(Ob, WoutT, b_out, out, nullptr, nullptr);
}

// Round 7
// 80.500 us; speedup vs baseline: 1.5596x; 1.0239x over previous
//
#include <hip/hip_runtime.h>

typedef __attribute__((ext_vector_type(8))) _Float16 f16x8;
typedef __attribute__((ext_vector_type(4))) _Float16 f16x4;
typedef __attribute__((ext_vector_type(4))) float f32x4;
typedef __attribute__((address_space(1))) const char gc_char;
typedef __attribute__((address_space(3))) char ls_char;

#define MFMA(a, b, c) __builtin_amdgcn_mfma_f32_16x16x32_f16((a), (b), (c), 0, 0, 0)
#define FENCE() asm volatile("" ::: "memory")
#define BARRIER() do { FENCE(); __builtin_amdgcn_s_barrier(); FENCE(); } while (0)
#define VMW(n) asm volatile("s_waitcnt vmcnt(" #n ")" ::: "memory")

static constexpr int SEQ = 4096;
static constexpr int EMB = 512;
static constexpr float QSCALE = 0.04419417382415922f; // 1/sqrt(512)

__device__ __forceinline__ void gl_lds16(const void* g, void* l) {
    __builtin_amdgcn_global_load_lds((gc_char*)g, (ls_char*)l, 16, 0, 0);
}

// ---------------- fused prep: cast x + LDS-tiled transpose-cast both W ----------------
__global__ void k_prep(const float* __restrict__ x, _Float16* __restrict__ xb,
                       const float* __restrict__ Wq, _Float16* __restrict__ WqT,
                       const float* __restrict__ Wo, _Float16* __restrict__ WoT) {
    const int bid = blockIdx.x, tid = threadIdx.x;
    if (bid < 4096) {
        long i = (long)bid * 256 + tid;
        const float4* p = (const float4*)x + i * 2;
        float4 a = p[0], b = p[1];
        f16x8 v;
        v[0] = (_Float16)a.x; v[1] = (_Float16)a.y; v[2] = (_Float16)a.z; v[3] = (_Float16)a.w;
        v[4] = (_Float16)b.x; v[5] = (_Float16)b.y; v[6] = (_Float16)b.z; v[7] = (_Float16)b.w;
        *(f16x8*)(xb + i * 8) = v;
    } else {
        __shared__ float Ls[64][65];
        int t = bid - 4096;
        const float* W; _Float16* WT; int N, k0, n0;
        if (t < 192) { W = Wq; WT = WqT; N = 1536; k0 = (t & 7) * 64; n0 = (t >> 3) * 64; }
        else { t -= 192; W = Wo; WT = WoT; N = 512; k0 = (t & 7) * 64; n0 = (t >> 3) * 64; }
        int c = tid & 63, r4 = tid >> 6;
#pragma unroll
        for (int i = 0; i < 16; ++i) {
            int row = i * 4 + r4;
            Ls[row][c] = W[(long)(k0 + row) * N + n0 + c];
        }
        __syncthreads();
#pragma unroll
        for (int i = 0; i < 16; ++i) {
            int row = i * 4 + r4;
            WT[(long)(n0 + row) * 512 + k0 + c] = (_Float16)Ls[c][row];
        }
    }
}

// ================= 128x256 tile, BK=64, 4-phase counted-vmcnt QKV GEMM =================
// Q/K row-major fp16 (Q scaled); V transposed to VT[b][e][k].
__launch_bounds__(512, 1) __global__
void k_gemm_qkv(const _Float16* __restrict__ A, const _Float16* __restrict__ BT,
                const float* __restrict__ bias,
                _Float16* __restrict__ Qo, _Float16* __restrict__ Ko, _Float16* __restrict__ VT) {
    extern __shared__ __align__(16) char smem[];
    const int tid = threadIdx.x, lane = tid & 63, w = tid >> 6, g = lane >> 4, f = lane & 15;
    const int wrow = w >> 2, wcol = w & 3;
    const int bid = blockIdx.x;
    const int swz = (bid & 7) * 96 + (bid >> 3); // bijective XCD swizzle (768)
    const int brow = swz / 6, bcol = swz - brow * 6;
    const long row0 = (long)brow * 128;
    const int col0 = bcol * 256;
    const char* Abase = (const char*)A + row0 * 1024;
    const char* Bbase = (const char*)BT + (long)col0 * 1024;

    f32x4 acc[4][4] = {};
    f16x8 a[2][2], breg[2][2][2];

    auto stageA = [&](int h, char* dst, int kt) {
        int rr = tid >> 3;
        int ch = (tid & 7) ^ (rr & 7);
        int grow = h * 32 + (rr & 31) + (rr >> 5) * 64;
        gl_lds16(Abase + (long)grow * 1024 + kt * 128 + ch * 16, dst + h * 8192 + tid * 16);
    };
    auto stageB = [&](int h, char* dst, int kt) {
#pragma unroll
        for (int it = 0; it < 2; ++it) {
            int s = it * 512 + tid;
            int cc = s >> 3;
            int ch = (s & 7) ^ (cc & 7);
            int gcol = h * 32 + (cc & 31) + (cc >> 5) * 64;
            gl_lds16(Bbase + (long)gcol * 1024 + kt * 128 + ch * 16,
                     dst + 16384 + h * 16384 + s * 16);
        }
    };
    auto ldA = [&](const char* buf, int mh) {
#pragma unroll
        for (int mi = 0; mi < 2; ++mi)
#pragma unroll
            for (int ks = 0; ks < 2; ++ks) {
                int rr = wrow * 32 + mi * 16 + f;
                int cl = ks * 4 + g;
                a[mi][ks] = *(const f16x8*)(buf + mh * 8192 + rr * 128 + ((cl ^ (rr & 7)) << 4));
            }
    };
    auto ldB = [&](const char* buf, int nh) {
#pragma unroll
        for (int ni = 0; ni < 2; ++ni)
#pragma unroll
            for (int ks = 0; ks < 2; ++ks) {
                int cc = wcol * 32 + ni * 16 + f;
                int cl = ks * 4 + g;
                breg[nh][ni][ks] =
                    *(const f16x8*)(buf + 16384 + nh * 16384 + cc * 128 + ((cl ^ (cc & 7)) << 4));
            }
    };
    auto mfma8 = [&](int mh, int nh) {
        __builtin_amdgcn_s_setprio(1);
#pragma unroll
        for (int mi = 0; mi < 2; ++mi)
#pragma unroll
            for (int ni = 0; ni < 2; ++ni)
#pragma unroll
                for (int ks = 0; ks < 2; ++ks)
                    acc[mh * 2 + mi][nh * 2 + ni] =
                        MFMA(a[mi][ks], breg[nh][ni][ks], acc[mh * 2 + mi][nh * 2 + ni]);
        __builtin_amdgcn_s_setprio(0);
    };

    stageB(0, smem, 0);
    stageA(0, smem, 0); stageA(1, smem, 0);
    stageB(1, smem, 0);
    VMW(3);
    BARRIER();

    for (int kt = 0; kt < 8; ++kt) {
        const char* cur = smem + (kt & 1) * 49152;
        char* nxt = smem + ((kt + 1) & 1) * 49152;
        const bool last = (kt == 7);
        ldA(cur, 0); ldB(cur, 0);
        if (!last) stageB(0, nxt, kt + 1);
        BARRIER();
        mfma8(0, 0);
        if (!last) { VMW(2); } else { VMW(0); }
        BARRIER();
        ldB(cur, 1);
        if (!last) { stageA(0, nxt, kt + 1); stageA(1, nxt, kt + 1); }
        BARRIER();
        mfma8(0, 1);
        BARRIER();
        ldA(cur, 1);
        if (!last) stageB(1, nxt, kt + 1);
        BARRIER();
        mfma8(1, 0);
        BARRIER();
        mfma8(1, 1);
        if (!last) { VMW(3); }
        BARRIER();
    }

    float bv[4];
#pragma unroll
    for (int ni = 0; ni < 4; ++ni) bv[ni] = bias[col0 + wcol * 64 + ni * 16 + f];

    if (col0 >= 1024) {
#pragma unroll
        for (int mi = 0; mi < 4; ++mi)
#pragma unroll
            for (int ni = 0; ni < 4; ++ni) {
                int r0 = wrow * 64 + mi * 16 + g * 4;
                int c = wcol * 64 + ni * 16 + f;
                f16x4 v4;
#pragma unroll
                for (int j = 0; j < 4; ++j) v4[j] = (_Float16)(acc[mi][ni][j] + bv[ni]);
                *(f16x4*)(smem + c * 256 + ((r0 * 2) ^ ((c & 7) << 4))) = v4;
            }
        __syncthreads();
        int bb = (int)(row0 >> 12);
        _Float16* vt = VT + ((long)bb * 512 + (col0 - 1024)) * 4096 + (row0 & 4095);
#pragma unroll
        for (int it = 0; it < 8; ++it) {
            int slot = it * 512 + tid;
            int e = slot >> 4, ch = slot & 15;
            f16x8 v = *(const f16x8*)(smem + e * 256 + ((ch * 16) ^ ((e & 7) << 4)));
            *(f16x8*)(vt + (long)e * 4096 + ch * 8) = v;
        }
    } else {
        const float sc = (col0 < 512) ? QSCALE : 1.0f;
#pragma unroll
        for (int mi = 0; mi < 4; ++mi)
#pragma unroll
            for (int ni = 0; ni < 4; ++ni)
#pragma unroll
                for (int j = 0; j < 4; ++j) {
                    int r = wrow * 64 + mi * 16 + g * 4 + j;
                    int c = wcol * 64 + ni * 16 + f;
                    float v = (acc[mi][ni][j] + bv[ni]) * sc;
                    int pc = ((c >> 3) + ((r >> 2) & 7) * 2) & 31;
                    *(_Float16*)(smem + r * 512 + pc * 16 + (c & 7) * 2) = (_Float16)v;
                }
        __syncthreads();
        _Float16* dst = (col0 < 512) ? Qo : Ko;
        int cofs = (col0 < 512) ? col0 : col0 - 512;
#pragma unroll
        for (int it = 0; it < 8; ++it) {
            int slot = it * 512 + tid;
            int r = slot >> 5, ch = slot & 31;
            int pc = (ch + ((r >> 2) & 7) * 2) & 31;
            f16x8 v = *(const f16x8*)(smem + r * 512 + pc * 16);
            *(f16x8*)(dst + (row0 + r) * 512 + cofs + ch * 8) = v;
        }
    }
}

// ======= fused windowed attention + output projection: QBLK=64, 512 thr =======
// Phase 1: QK^T -> softmax -> PV (oacc in regs). Phase 2: att->LDS, out = att @ WoutT + b.
__launch_bounds__(512, 1) __global__
void k_attn(const _Float16* __restrict__ Qb, const _Float16* __restrict__ Kb,
            const _Float16* __restrict__ VT, const _Float16* __restrict__ WoT,
            const float* __restrict__ bout, float* __restrict__ Out) {
    extern __shared__ __align__(16) char smem[];
    char* buf[2] = { smem, smem + 49152 };
    char* Pl = smem + 98304;
    float* Mp = (float*)(smem + 123904);
    float* Lp = (float*)(smem + 124928);

    const int tid = threadIdx.x, w = tid >> 6, lane = tid & 63, g = lane >> 4, f = lane & 15;
    const int rh = w >> 2, kh = w & 3;
    const int bid = blockIdx.x;
    const int swzb = (bid & 7) * 32 + (bid >> 3);
    const int b = swzb >> 6, qt = swzb & 63;
    const int q0 = qt * 64, kbase = q0 - 64;
    const long bofs = (long)b * SEQ;

    f16x8 qf[2][16];
#pragma unroll
    for (int mt = 0; mt < 2; ++mt) {
        const _Float16* qr = Qb + (bofs + q0 + rh * 32 + mt * 16 + f) * EMB + g * 8;
#pragma unroll
        for (int ks = 0; ks < 16; ++ks) qf[mt][ks] = *(const f16x8*)(qr + ks * 32);
    }

    auto stageK = [&](int ec, char* dst) {
#pragma unroll
        for (int it = 0; it < 6; ++it) {
            int slot = it * 512 + tid;
            int r = slot >> 4, c = slot & 15;
            int cs = c ^ (r & 7);
            int key = min(max(kbase + r, 0), SEQ - 1);
            gl_lds16(Kb + (bofs + key) * EMB + ec * 128 + cs * 8, dst + slot * 16);
        }
    };
    auto stageVT = [&](int ec, char* dst) {
#pragma unroll
        for (int it = 0; it < 6; ++it) {
            int slot = it * 512 + tid;
            int r = slot / 24, c = slot - r * 24;
            int cs = c ^ (r & 7);
            int k0 = min(max(kbase + cs * 8, 0), SEQ - 8);
            gl_lds16(VT + ((long)b * 512 + ec * 128 + r) * 4096 + k0, dst + slot * 16);
        }
    };

    f32x4 sacc[2][3] = {};
    stageK(0, buf[0]);
    __syncthreads();
    for (int ec = 0; ec < 4; ++ec) {
        if (ec < 3) stageK(ec + 1, buf[(ec + 1) & 1]);
        else stageVT(0, buf[0]);
        const char* kb = buf[ec & 1];
#pragma unroll
        for (int kk = 0; kk < 4; ++kk) {
#pragma unroll
            for (int t = 0; t < 3; ++t) {
                int n = kh * 48 + t * 16 + f;
                f16x8 bf = *(const f16x8*)(kb + n * 256 + (((kk * 4 + g) ^ (n & 7)) << 4));
#pragma unroll
                for (int mt = 0; mt < 2; ++mt)
                    sacc[mt][t] = MFMA(qf[mt][ec * 4 + kk], bf, sacc[mt][t]);
            }
        }
        __syncthreads();
    }

    float m[2][4] = {{-3e30f, -3e30f, -3e30f, -3e30f}, {-3e30f, -3e30f, -3e30f, -3e30f}};
    float l[2][4] = {};
#pragma unroll
    for (int mt = 0; mt < 2; ++mt)
#pragma unroll
        for (int t = 0; t < 3; ++t) {
            int key = kbase + kh * 48 + t * 16 + f;
            bool kv = (key >= 0) && (key < SEQ);
#pragma unroll
            for (int j = 0; j < 4; ++j) {
                int d = key - (q0 + rh * 32 + mt * 16 + g * 4 + j);
                bool valid = kv && (d >= -64) && (d <= 64);
                float s = valid ? sacc[mt][t][j] : -3e30f;
                sacc[mt][t][j] = s;
                m[mt][j] = fmaxf(m[mt][j], s);
            }
        }
#pragma unroll
    for (int mt = 0; mt < 2; ++mt)
#pragma unroll
        for (int j = 0; j < 4; ++j) {
            m[mt][j] = fmaxf(m[mt][j], __shfl_xor(m[mt][j], 1));
            m[mt][j] = fmaxf(m[mt][j], __shfl_xor(m[mt][j], 2));
            m[mt][j] = fmaxf(m[mt][j], __shfl_xor(m[mt][j], 4));
            m[mt][j] = fmaxf(m[mt][j], __shfl_xor(m[mt][j], 8));
        }
    if (f == 0) {
#pragma unroll
        for (int mt = 0; mt < 2; ++mt)
#pragma unroll
            for (int j = 0; j < 4; ++j)
                Mp[kh * 64 + rh * 32 + mt * 16 + g * 4 + j] = m[mt][j];
    }
    __syncthreads();
#pragma unroll
    for (int mt = 0; mt < 2; ++mt)
#pragma unroll
        for (int j = 0; j < 4; ++j) {
            int r = rh * 32 + mt * 16 + g * 4 + j;
            m[mt][j] = fmaxf(fmaxf(Mp[r], Mp[64 + r]), fmaxf(Mp[128 + r], Mp[192 + r]));
        }
#pragma unroll
    for (int mt = 0; mt < 2; ++mt)
#pragma unroll
        for (int t = 0; t < 3; ++t)
#pragma unroll
            for (int j = 0; j < 4; ++j) {
                float p = __expf(sacc[mt][t][j] - m[mt][j]);
                sacc[mt][t][j] = p;
                l[mt][j] += p;
            }
#pragma unroll
    for (int mt = 0; mt < 2; ++mt)
#pragma unroll
        for (int j = 0; j < 4; ++j) {
            l[mt][j] += __shfl_xor(l[mt][j], 1);
            l[mt][j] += __shfl_xor(l[mt][j], 2);
            l[mt][j] += __shfl_xor(l[mt][j], 4);
            l[mt][j] += __shfl_xor(l[mt][j], 8);
        }
    if (f == 0) {
#pragma unroll
        for (int mt = 0; mt < 2; ++mt)
#pragma unroll
            for (int j = 0; j < 4; ++j)
                Lp[kh * 64 + rh * 32 + mt * 16 + g * 4 + j] = l[mt][j];
    }
#pragma unroll
    for (int mt = 0; mt < 2; ++mt)
#pragma unroll
        for (int t = 0; t < 3; ++t)
#pragma unroll
            for (int j = 0; j < 4; ++j)
                *(_Float16*)(Pl + (rh * 32 + mt * 16 + g * 4 + j) * 400 +
                             (kh * 48 + t * 16 + f) * 2) = (_Float16)sacc[mt][t][j];
    __syncthreads();

    float rl[2][4];
#pragma unroll
    for (int mt = 0; mt < 2; ++mt)
#pragma unroll
        for (int j = 0; j < 4; ++j) {
            int r = rh * 32 + mt * 16 + g * 4 + j;
            rl[mt][j] = 1.0f / (Lp[r] + Lp[64 + r] + Lp[128 + r] + Lp[192 + r]);
        }

    f16x8 pf[2][6];
#pragma unroll
    for (int mt = 0; mt < 2; ++mt)
#pragma unroll
        for (int kc = 0; kc < 6; ++kc)
            pf[mt][kc] = *(const f16x8*)(Pl + (rh * 32 + mt * 16 + f) * 400 + kc * 64 + g * 16);

    // ---- PV: accumulate all 4 e-chunks in registers ----
    f32x4 oacc[4][2][2] = {};
#pragma unroll
    for (int ec = 0; ec < 4; ++ec) {
        if (ec < 3) stageVT(ec + 1, buf[(ec + 1) & 1]);
        const char* vb = buf[ec & 1];
#pragma unroll
        for (int kc = 0; kc < 6; ++kc) {
#pragma unroll
            for (int nt = 0; nt < 2; ++nt) {
                int e = kh * 32 + nt * 16 + f;
                f16x8 vf = *(const f16x8*)(vb + e * 384 + (((kc * 4 + g) ^ (e & 7)) << 4));
#pragma unroll
                for (int mt = 0; mt < 2; ++mt)
                    oacc[ec][mt][nt] = MFMA(pf[mt][kc], vf, oacc[ec][mt][nt]);
            }
        }
        if (ec < 3) __syncthreads();
    }

    // ================= phase 2: fused output projection =================
    __syncthreads(); // all PV reads done; entire LDS reusable
    char* att = smem;                         // [64 rows][1024B] XOR-swizzled
    char* wb0 = smem + 65536;                 // W unit dbuf, 32KB each
    char* wb1 = smem + 98304;

    auto stageW = [&](int u, char* dst) {
#pragma unroll
        for (int i = 0; i < 4; ++i) {
            int s = i * 512 + tid;
            int col = s >> 2, ch = s & 3;
            gl_lds16(WoT + (long)col * 512 + u * 32 + ((ch ^ (col & 3)) * 8), dst + s * 16);
        }
    };
    stageW(0, wb0);
    stageW(1, wb1);
    // attended -> att LDS (scaled, fp16); write (col*2)^((row&7)<<4), read same
#pragma unroll
    for (int ec = 0; ec < 4; ++ec)
#pragma unroll
        for (int mt = 0; mt < 2; ++mt)
#pragma unroll
            for (int nt = 0; nt < 2; ++nt)
#pragma unroll
                for (int j = 0; j < 4; ++j) {
                    int row = rh * 32 + mt * 16 + g * 4 + j;
                    int col = ec * 128 + kh * 32 + nt * 16 + f;
                    *(_Float16*)(att + row * 1024 + ((col * 2) ^ ((row & 7) << 4))) =
                        (_Float16)(oacc[ec][mt][nt][j] * rl[mt][j]);
                }
    __syncthreads(); // drains vmcnt: att + W units 0,1 ready

    float bv2[8];
#pragma unroll
    for (int nt = 0; nt < 8; ++nt) bv2[nt] = bout[kh * 128 + nt * 16 + f];

    f32x4 acc2[2][8] = {};
    for (int u = 0; u < 16; ++u) {
        const char* wcur = (u & 1) ? wb1 : wb0;
        f16x8 a2[2];
#pragma unroll
        for (int mt = 0; mt < 2; ++mt) {
            int row = rh * 32 + mt * 16 + f;
            a2[mt] = *(const f16x8*)(att + row * 1024 + ((u * 64 + g * 16) ^ ((row & 7) << 4)));
        }
        __builtin_amdgcn_s_setprio(1);
#pragma unroll
        for (int nt = 0; nt < 8; ++nt) {
            int col = kh * 128 + nt * 16 + f;
            f16x8 b2 = *(const f16x8*)(wcur + col * 64 + ((g * 16) ^ ((col & 3) << 4)));
#pragma unroll
            for (int mt = 0; mt < 2; ++mt)
                acc2[mt][nt] = MFMA(a2[mt], b2, acc2[mt][nt]);
        }
        __builtin_amdgcn_s_setprio(0);
        BARRIER();
        if (u + 2 < 16) {
            stageW(u + 2, (u & 1) ? wb1 : wb0);
            VMW(4);
        } else {
            VMW(0);
        }
        BARRIER();
    }

#pragma unroll
    for (int mt = 0; mt < 2; ++mt)
#pragma unroll
        for (int nt = 0; nt < 8; ++nt) {
            long r0 = bofs + q0 + rh * 32 + mt * 16 + g * 4;
            int c = kh * 128 + nt * 16 + f;
#pragma unroll
            for (int j = 0; j < 4; ++j)
                Out[(r0 + j) * 512 + c] = acc2[mt][nt][j] + bv2[nt];
        }
}

extern "C" void kernel_launch(void* const* d_in, const int* in_sizes, int n_in,
                              void* d_out, int out_size, void* d_ws, size_t ws_size,
                              hipStream_t stream) {
    const float* x     = (const float*)d_in[0];
    const float* W_qkv = (const float*)d_in[1];
    const float* b_qkv = (const float*)d_in[2];
    const float* W_out = (const float*)d_in[3];
    const float* b_out = (const float*)d_in[4];

    char* ws = (char*)d_ws;
    _Float16* xb    = (_Float16*)(ws);                         // 16 MiB
    _Float16* WqkvT = (_Float16*)(ws + 16777216);              // 1.5 MiB
    _Float16* WoutT = (_Float16*)(ws + 16777216 + 1572864);    // 0.5 MiB
    _Float16* Qb    = (_Float16*)(ws + 18874368);              // 16 MiB
    _Float16* Kb    = (_Float16*)(ws + 18874368 + 16777216);   // 16 MiB
    _Float16* VT    = (_Float16*)(ws + 18874368 + 33554432);   // 16 MiB [b][e][k]
    float* out = (float*)d_out;

    (void)hipFuncSetAttribute((const void*)k_gemm_qkv,
                              hipFuncAttributeMaxDynamicSharedMemorySize, 98304);
    (void)hipFuncSetAttribute((const void*)k_attn,
                              hipFuncAttributeMaxDynamicSharedMemorySize, 131072);

    k_prep<<<4352, 256, 0, stream>>>(x, xb, W_qkv, WqkvT, W_out, WoutT);
    k_gemm_qkv<<<768, 512, 98304, stream>>>(xb, WqkvT, b_qkv, Qb, Kb, VT);
    k_attn<<<256, 512, 131072, stream>>>(Qb, Kb, VT, WoutT, b_out, out);
}